// Round 2
// baseline (1570.507 us; speedup 1.0000x reference)
//
#include <hip/hip_runtime.h>

#define NN 100000
#define NE 1600000
#define DIM 128
#define EDIM 16
#define NL 3

typedef unsigned short u16;
typedef unsigned int u32;
typedef __attribute__((ext_vector_type(8))) short bf16x8;
typedef __attribute__((ext_vector_type(4))) float f32x4;

__device__ __forceinline__ float b2f(u16 u){ u32 x = ((u32)u)<<16; float f; __builtin_memcpy(&f,&x,4); return f; }
__device__ __forceinline__ float b2f_lo(u32 u){ u32 x = u<<16; float f; __builtin_memcpy(&f,&x,4); return f; }
__device__ __forceinline__ float b2f_hi(u32 u){ u32 x = u & 0xffff0000u; float f; __builtin_memcpy(&f,&x,4); return f; }
__device__ __forceinline__ u16 f2b(float f){ u32 x; __builtin_memcpy(&x,&f,4); u32 r = (x + 0x7fffu + ((x>>16)&1u))>>16; return (u16)r; }

// ---------------- dtype probes ----------------
__global__ void k_probe_f(const u16* __restrict__ x, int* fflag){
  __shared__ int cnt;
  if (threadIdx.x==0) cnt = 0;
  __syncthreads();
  int sane = 0;
  for (int j=threadIdx.x; j<2048; j+=256){
    u16 w = x[j];
    int e = (w>>7)&0xFF;
    if (w==0 || (e>=100 && e<=140)) sane++;
  }
  atomicAdd(&cnt, sane);
  __syncthreads();
  if (threadIdx.x==0) *fflag = (cnt < 1900) ? 1 : 0;   // 1 => float32
}
__global__ void k_probe_i(const int* __restrict__ ei, int* iflag){
  int j = blockIdx.x*256 + threadIdx.x;
  if (j < 1024){ if (ei[2*j+1] != 0) atomicOr(iflag, 1); }  // !=0 => int32
}

// ---------------- utility ----------------
__global__ void k_zero32(int* p, int n){ int i = blockIdx.x*256 + threadIdx.x; if (i<n) p[i]=0; }
__global__ void k_zerof(float* p, int n){ int i = blockIdx.x*256 + threadIdx.x; if (i<n) p[i]=0.f; }

__global__ void k_x2f(const void* __restrict__ x, float* __restrict__ h, const int* __restrict__ fflag){
  int i = blockIdx.x*256 + threadIdx.x;
  if (i >= NN*DIM/4) return;
  float4 v;
  if (*fflag) v = ((const float4*)x)[i];
  else {
    uint2 u = ((const uint2*)x)[i];
    v = make_float4(b2f_lo(u.x), b2f_hi(u.x), b2f_lo(u.y), b2f_hi(u.y));
  }
  ((float4*)h)[i] = v;
}

// canonical bf16 params; Wl/Wr/Wf stored TRANSPOSED (dst[c][k] = src[k][c])
// WET = We transposed per layer: WeT[l][c][k] = We[l][k][c]
#define SEG_WL    0
#define SEG_WR    49152
#define SEG_WE    98304
#define SEG_ATT   104448
#define SEG_GAM   104832
#define SEG_BET   105216
#define SEG_WF    105600
#define SEG_BF    121984
#define SEG_BL    122112
#define SEG_BR    122496
#define SEG_WET   122880
#define SEG_TOTAL 129024

__global__ void k_cvt_params(const void* Wl, const void* Wr, const void* We, const void* att,
                             const void* gam, const void* bet, const void* Wf, const void* bf,
                             const void* bl, const void* br,
                             u16* __restrict__ dst, const int* __restrict__ fflag){
  int i = blockIdx.x*256 + threadIdx.x;
  if (i >= SEG_TOTAL) return;
  const void* src; int off;
  if (i < SEG_WR){                       // Wl^T
    int o = i - SEG_WL; int l = o>>14, r = o&16383, c = r>>7, k = r&127;
    src = Wl; off = (l<<14)|(k<<7)|c;
  } else if (i < SEG_WE){                // Wr^T
    int o = i - SEG_WR; int l = o>>14, r = o&16383, c = r>>7, k = r&127;
    src = Wr; off = (l<<14)|(k<<7)|c;
  } else if (i < SEG_ATT){ src = We;  off = i - SEG_WE; }
  else if (i < SEG_GAM)  { src = att; off = i - SEG_ATT; }
  else if (i < SEG_BET)  { src = gam; off = i - SEG_GAM; }
  else if (i < SEG_WF)   { src = bet; off = i - SEG_BET; }
  else if (i < SEG_BF){                  // Wf^T
    int o = i - SEG_WF; int c = o>>7, k = o&127;
    src = Wf; off = (k<<7)|c;
  }
  else if (i < SEG_BL)   { src = bf;  off = i - SEG_BF; }
  else if (i < SEG_BR)   { src = bl;  off = i - SEG_BL; }
  else if (i < SEG_WET)  { src = br;  off = i - SEG_BR; }
  else {                                 // We^T: [l][c][k] <- We[l][k][c]
    int o = i - SEG_WET; int l = o>>11, r = o&2047, c = r>>4, k = r&15;
    src = We; off = (l<<11)|(k<<7)|c;
  }
  dst[i] = (*fflag) ? f2b(((const float*)src)[off]) : ((const u16*)src)[off];
}

// ---------------- CSR build ----------------
__global__ void k_count(const int* __restrict__ ei, const int* __restrict__ iflag, int* __restrict__ counts){
  int e = blockIdx.x*256 + threadIdx.x; if (e >= NE) return;
  int d;
  if (*iflag) d = ei[NE + e];
  else        d = (int)((const long long*)ei)[NE + e];
  atomicAdd(&counts[d], 1);
}
__global__ void k_scanA(const int* __restrict__ counts, int* __restrict__ offs, int* __restrict__ bsums){
  __shared__ int s[1024];
  int t = threadIdx.x; int i = blockIdx.x*1024 + t;
  int v = (i < NN) ? counts[i] : 0;
  s[t] = v; __syncthreads();
  for (int off=1; off<1024; off<<=1){
    int x = (t>=off) ? s[t-off] : 0;
    __syncthreads();
    s[t] += x;
    __syncthreads();
  }
  if (i < NN) offs[i] = s[t] - v;
  if (t == 1023) bsums[blockIdx.x] = s[1023];
}
__global__ void k_scanB(int* bsums, int* offs, int nb){
  if (threadIdx.x==0 && blockIdx.x==0){
    int run = 0;
    for (int j=0;j<nb;j++){ int tmp=bsums[j]; bsums[j]=run; run+=tmp; }
    offs[NN] = run;
  }
}
__global__ void k_scanC(int* __restrict__ offs, const int* __restrict__ bsums){
  int i = blockIdx.x*256 + threadIdx.x;
  if (i < NN) offs[i] += bsums[i>>10];
}

// fill CSR: srcs + edge_attr permuted into CSR order as bf16 (eperm)
__global__ void k_fill(const int* __restrict__ ei, const int* __restrict__ iflag,
                       const int* __restrict__ offs, int* __restrict__ counts,
                       int* __restrict__ srcs, u16* __restrict__ eperm,
                       const void* __restrict__ eattr, const int* __restrict__ fflag){
  int e = blockIdx.x*256 + threadIdx.x; if (e >= NE) return;
  int s, d;
  if (*iflag){ s = ei[e]; d = ei[NE + e]; }
  else { const long long* e64 = (const long long*)ei; s = (int)e64[e]; d = (int)e64[NE + e]; }
  int pos = offs[d] + atomicAdd(&counts[d], 1);
  srcs[pos] = s;
  uint4 lo, hi;
  if (*fflag){
    const float4* s4 = (const float4*)((const float*)eattr + (size_t)e*EDIM);
    float4 a = s4[0], b = s4[1], c = s4[2], dd = s4[3];
    lo.x = (u32)f2b(a.x) | ((u32)f2b(a.y)<<16); lo.y = (u32)f2b(a.z) | ((u32)f2b(a.w)<<16);
    lo.z = (u32)f2b(b.x) | ((u32)f2b(b.y)<<16); lo.w = (u32)f2b(b.z) | ((u32)f2b(b.w)<<16);
    hi.x = (u32)f2b(c.x) | ((u32)f2b(c.y)<<16); hi.y = (u32)f2b(c.z) | ((u32)f2b(c.w)<<16);
    hi.z = (u32)f2b(dd.x)| ((u32)f2b(dd.y)<<16);hi.w = (u32)f2b(dd.z)| ((u32)f2b(dd.w)<<16);
  } else {
    const uint4* s4 = (const uint4*)((const u16*)eattr + (size_t)e*EDIM);
    lo = s4[0]; hi = s4[1];
  }
  uint4* dst = (uint4*)(eperm + (size_t)pos*EDIM);
  dst[0] = lo; dst[1] = hi;
}

// ---------------- MFMA node GEMM: out[n][c] = sum_k in[n][k]*W[k][c] + b[c] ----------------
// WT = transposed weight [c][k] bf16. 64 rows x 128 cols per block, 4 waves.
#define LSTR 136   // padded LDS row stride (bf16 elems): +16B breaks bank conflicts
__global__ __launch_bounds__(256) void k_gemm(const float* __restrict__ in,
    const u16* __restrict__ WT0, const u16* __restrict__ b0, void* __restrict__ out0,
    const u16* __restrict__ WT1, const u16* __restrict__ b1, void* __restrict__ out1,
    int store_f32, const int* __restrict__ fflag)
{
  __shared__ __align__(16) u16 Xs[64*LSTR];
  __shared__ __align__(16) u16 Ws[128*LSTR];
  const u16* WT = blockIdx.y ? WT1 : WT0;
  const u16* bi = blockIdx.y ? b1 : b0;
  void* out     = blockIdx.y ? out1 : out0;
  int t = threadIdx.x;
  int n0 = blockIdx.x*64;
  // stage W^T (128x128 bf16 = 2048 uint4), coalesced
  const uint4* w4 = (const uint4*)WT;
  for (int p = t; p < 2048; p += 256){
    int c = p >> 4, k16 = p & 15;
    *(uint4*)&Ws[c*LSTR + k16*8] = w4[p];
  }
  // stage X (64x128 f32 -> bf16)
  for (int p = t; p < 2048; p += 256){
    int r = p >> 5, c4 = p & 31;
    int n = n0 + r;
    uint2 pk;
    if (n < NN){
      float4 v = *(const float4*)(in + (size_t)n*DIM + c4*4);
      pk.x = (u32)f2b(v.x) | ((u32)f2b(v.y)<<16);
      pk.y = (u32)f2b(v.z) | ((u32)f2b(v.w)<<16);
    } else pk = make_uint2(0,0);
    *(uint2*)&Xs[r*LSTR + c4*4] = pk;
  }
  __syncthreads();
  int lane = t & 63, wv = t >> 6;
  int m = lane & 15, q = lane >> 4;
  f32x4 acc[8];
  #pragma unroll
  for (int i=0;i<8;i++) acc[i] = (f32x4){0.f,0.f,0.f,0.f};
  #pragma unroll
  for (int ks=0; ks<4; ks++){
    bf16x8 af = *(const bf16x8*)&Xs[(wv*16 + m)*LSTR + ks*32 + q*8];
    #pragma unroll
    for (int nt=0; nt<8; nt++){
      bf16x8 bfr = *(const bf16x8*)&Ws[(nt*16 + m)*LSTR + ks*32 + q*8];
      acc[nt] = __builtin_amdgcn_mfma_f32_16x16x32_bf16(af, bfr, acc[nt], 0, 0, 0);
    }
  }
  bool f32out = store_f32 && (*fflag);
  #pragma unroll
  for (int nt=0; nt<8; nt++){
    int col = nt*16 + m;
    float bvv = b2f(bi[col]);
    #pragma unroll
    for (int r=0;r<4;r++){
      int row = n0 + wv*16 + q*4 + r;
      if (row < NN){
        float val = acc[nt][r] + bvv;
        if (f32out) ((float*)out)[(size_t)row*DIM + col] = val;
        else        ((u16*)out)[(size_t)row*DIM + col] = f2b(val);
      }
    }
  }
}

// ---------------- attention ----------------
// One wave per node (grid-stride). Per 16-edge CSR tile, el = eperm_tile @ We on the
// matrix pipe (A = [16e x 16k] zero-padded to K=32, B = We^T fragments loaded from the
// pre-transposed global segment). D scattered into a per-wave XOR-swizzled LDS tile
// [16][128] f32 (swizzle: ch ^= (row&4)<<2 -> 2-way write banks = free, uniform-XOR read),
// then consumed by the online-softmax scalar loop with defer-max fast path.
__global__ __launch_bounds__(256,4) void k_attn(const int* __restrict__ offs, const int* __restrict__ srcs,
    const u16* __restrict__ eperm, const u16* __restrict__ WeT, const u16* __restrict__ att,
    const u16* __restrict__ gl, const u16* __restrict__ gr, float* __restrict__ agg)
{
  __shared__ __align__(16) float sEl[4][16*128];   // per-wave el tiles, 32 KB total
  int t = threadIdx.x;
  int lane = t & 63, wv = t >> 6;
  int m = lane & 15, q = lane >> 4;
  // loop-invariant B fragments of We^T: bwe[tc] holds WeT[tc*16+m][q*8..q*8+7] (zero for k>=16)
  bf16x8 bwe[8];
  #pragma unroll
  for (int tc = 0; tc < 8; ++tc){
    if (q < 2) bwe[tc] = *(const bf16x8*)&WeT[(tc*16 + m)*16 + q*8];
    else       bwe[tc] = (bf16x8){0,0,0,0,0,0,0,0};
  }
  float att0 = b2f(att[2*lane]), att1 = b2f(att[2*lane+1]);
  float* el = &sEl[wv][0];
  const u32* glv = (const u32*)gl;
  const float THR = 8.f;

  for (int node = blockIdx.x*4 + wv; node < NN; node += gridDim.x*4){
    u32 g = ((const u32*)gr)[(size_t)node*64 + lane];
    float gr0 = b2f_lo(g), gr1 = b2f_hi(g);
    float ms[4], ds[4], o0[4], o1[4];
    #pragma unroll
    for (int i=0;i<4;i++){ ms[i] = -INFINITY; ds[i]=0.f; o0[i]=0.f; o1[i]=0.f; }
    int beg = offs[node], end = offs[node+1];
    for (int tb = beg; tb < end; tb += 16){
      // ---- el tile on matrix pipe ----
      bf16x8 af = (bf16x8){0,0,0,0,0,0,0,0};
      if (q < 2){
        int eidx = tb + m; eidx = eidx < NE ? eidx : NE-1;   // clamp tile overrun
        af = *(const bf16x8*)&eperm[(size_t)eidx*EDIM + q*8];
      }
      #pragma unroll
      for (int tc = 0; tc < 8; ++tc){
        f32x4 d = __builtin_amdgcn_mfma_f32_16x16x32_bf16(af, bwe[tc], (f32x4){0.f,0.f,0.f,0.f}, 0, 0, 0);
        #pragma unroll
        for (int r = 0; r < 4; ++r){
          int row = q*4 + r;                                  // edge row
          el[(row<<7) + ((tc*16 + m) ^ ((row&4)<<2))] = d[r]; // swizzled channel
        }
      }
      // same-wave LDS write->read: in-order DS pipe + compiler lgkmcnt, no barrier needed
      int tend = end < tb + 16 ? end : tb + 16;
      int e = tb;
      for (; e + 4 <= tend; e += 4){
        int sidx[4];
        #pragma unroll
        for (int i=0;i<4;i++) sidx[i] = srcs[e+i];
        u32 gx[4];
        #pragma unroll
        for (int i=0;i<4;i++) gx[i] = glv[((u32)sidx[i]<<6) | (u32)lane];
        float2 ev[4];
        #pragma unroll
        for (int i=0;i<4;i++){
          int erow = e - tb + i;
          ev[i] = *(const float2*)&el[(erow<<7) + ((2*lane) ^ ((erow&4)<<2))];
        }
        #pragma unroll
        for (int i=0;i<4;i++){
          float xj0 = b2f_lo(gx[i]), xj1 = b2f_hi(gx[i]);
          float e0 = xj0 + gr0 + ev[i].x;
          float e1 = xj1 + gr1 + ev[i].y;
          e0 = fmaxf(e0, 0.2f*e0);
          e1 = fmaxf(e1, 0.2f*e1);
          float part = e0*att0 + e1*att1;
          part += __shfl_xor(part, 1);
          part += __shfl_xor(part, 2);
          part += __shfl_xor(part, 4);
          part += __shfl_xor(part, 8);
          if (__all(part <= ms[i] + THR)) {      // defer-max fast path
            float pp = __expf(part - ms[i]);
            ds[i] += pp;
            o0[i] += pp*xj0;
            o1[i] += pp*xj1;
          } else {
            float nm = fmaxf(ms[i], part);
            float sc = __expf(ms[i] - nm);       // -inf -> 0 on first edge
            float pp = __expf(part - nm);
            ds[i] = ds[i]*sc + pp;
            o0[i] = o0[i]*sc + pp*xj0;
            o1[i] = o1[i]*sc + pp*xj1;
            ms[i] = nm;
          }
        }
      }
      for (; e < tend; ++e){
        int s = srcs[e];
        u32 gx = glv[((u32)s<<6) | (u32)lane];
        int erow = e - tb;
        float2 ev = *(const float2*)&el[(erow<<7) + ((2*lane) ^ ((erow&4)<<2))];
        float xj0 = b2f_lo(gx), xj1 = b2f_hi(gx);
        float e0 = xj0 + gr0 + ev.x;
        float e1 = xj1 + gr1 + ev.y;
        e0 = fmaxf(e0, 0.2f*e0);
        e1 = fmaxf(e1, 0.2f*e1);
        float part = e0*att0 + e1*att1;
        part += __shfl_xor(part, 1);
        part += __shfl_xor(part, 2);
        part += __shfl_xor(part, 4);
        part += __shfl_xor(part, 8);
        if (__all(part <= ms[0] + THR)) {
          float pp = __expf(part - ms[0]);
          ds[0] += pp;
          o0[0] += pp*xj0;
          o1[0] += pp*xj1;
        } else {
          float nm = fmaxf(ms[0], part);
          float sc = __expf(ms[0] - nm);
          float pp = __expf(part - nm);
          ds[0] = ds[0]*sc + pp;
          o0[0] = o0[0]*sc + pp*xj0;
          o1[0] = o1[0]*sc + pp*xj1;
          ms[0] = nm;
        }
      }
    }
    // merge states (guard -inf: empty state contributes 0)
    float M = fmaxf(fmaxf(ms[0],ms[1]), fmaxf(ms[2],ms[3]));
    float D = 0.f, P0 = 0.f, P1 = 0.f;
    #pragma unroll
    for (int i=0;i<4;i++){
      if (ms[i] != -INFINITY){
        float sc = __expf(ms[i] - M);
        D += sc*ds[i]; P0 += sc*o0[i]; P1 += sc*o1[i];
      }
    }
    float inv = 1.f/(D + 1e-16f);
    ((float2*)agg)[(size_t)node*64 + lane] = make_float2(P0*inv, P1*inv);
  }
}

// ---------------- batch norm ----------------
__global__ __launch_bounds__(256) void k_bnstats(const float* __restrict__ agg, float* __restrict__ stats){
  int t = threadIdx.x;
  int p = t & 63;
  int rg = t >> 6;
  float s0=0,s1=0,q0=0,q1=0;
  for (int r = blockIdx.x*4 + rg; r < NN; r += 256*4){
    float2 v = ((const float2*)agg)[(size_t)r*64 + p];
    s0 += v.x; s1 += v.y; q0 += v.x*v.x; q1 += v.y*v.y;
  }
  int c0 = 2*p;
  atomicAdd(&stats[c0],     s0); atomicAdd(&stats[c0+1],     s1);
  atomicAdd(&stats[DIM+c0], q0); atomicAdd(&stats[DIM+c0+1], q1);
}

__global__ __launch_bounds__(256) void k_bnapply(const float* __restrict__ agg, const float* __restrict__ stats,
    const u16* __restrict__ gamma, const u16* __restrict__ beta, float* __restrict__ h){
  int i = blockIdx.x*256 + threadIdx.x;
  if (i >= NN*64) return;
  int p = i & 63; int c0 = 2*p;
  float2 v = ((const float2*)agg)[i];
  const float invN = 1.f/(float)NN;
  float mu0 = stats[c0]*invN,   mu1 = stats[c0+1]*invN;
  float va0 = stats[DIM+c0]*invN   - mu0*mu0;
  float va1 = stats[DIM+c0+1]*invN - mu1*mu1;
  float rs0 = rsqrtf(fmaxf(va0, 0.f) + 1e-5f), rs1 = rsqrtf(fmaxf(va1, 0.f) + 1e-5f);
  float y0 = (v.x - mu0)*rs0*b2f(gamma[c0])   + b2f(beta[c0]);
  float y1 = (v.y - mu1)*rs1*b2f(gamma[c0+1]) + b2f(beta[c0+1]);
  y0 = fmaxf(y0, 0.02f*y0);
  y1 = fmaxf(y1, 0.02f*y1);
  ((float2*)h)[i] = make_float2(y0, y1);
}

// ---------------- launch ----------------
extern "C" void kernel_launch(void* const* d_in, const int* in_sizes, int n_in,
                              void* d_out, int out_size, void* d_ws, size_t ws_size,
                              hipStream_t stream){
  (void)in_sizes; (void)n_in; (void)out_size; (void)ws_size;
  const void* x    = d_in[0];
  const int* ei    = (const int*)d_in[1];
  const void* eattr= d_in[2];
  // d_in[9] = conv bias: cancels under BN mean-subtraction, skipped
  char* p = (char*)d_ws;
  auto alloc = [&](size_t b)->void*{ void* q = p; p += (b + 255) & ~(size_t)255; return q; };
  float* h      = (float*)alloc((size_t)NN*DIM*4);    // features; also attn output + BN in-place
  u16*   gl     = (u16*)  alloc((size_t)NN*DIM*2);
  u16*   gr     = (u16*)  alloc((size_t)NN*DIM*2);
  int*   offs   = (int*)  alloc((size_t)(NN+1)*4);
  int*   counts = (int*)  alloc((size_t)NN*4);
  int*   srcs   = (int*)  alloc((size_t)NE*4);
  u16*   eperm  = (u16*)  alloc((size_t)NE*EDIM*2);   // edge_attr in CSR order, bf16
  float* stats  = (float*)alloc(256*4);
  int*   bsums  = (int*)  alloc(128*4);
  int*   flags  = (int*)  alloc(8);                   // [0]=fflag, [1]=iflag
  u16*   cpar   = (u16*)  alloc((size_t)SEG_TOTAL*2);

  int* fflag = flags;
  int* iflag = flags + 1;

  k_zero32<<<1,256,0,stream>>>(flags, 2);
  k_probe_f<<<1,256,0,stream>>>((const u16*)x, fflag);
  k_probe_i<<<4,256,0,stream>>>(ei, iflag);
  k_cvt_params<<<(SEG_TOTAL+255)/256,256,0,stream>>>(d_in[3], d_in[5], d_in[7], d_in[8],
      d_in[10], d_in[11], d_in[12], d_in[13], d_in[4], d_in[6], cpar, fflag);
  const u16* cWlT= cpar + SEG_WL;  const u16* cWrT= cpar + SEG_WR;
  const u16* cAtt= cpar + SEG_ATT;
  const u16* cGam= cpar + SEG_GAM; const u16* cBet= cpar + SEG_BET;
  const u16* cWfT= cpar + SEG_WF;  const u16* cBf = cpar + SEG_BF;
  const u16* cBl = cpar + SEG_BL;  const u16* cBr = cpar + SEG_BR;
  const u16* cWeT= cpar + SEG_WET;

  k_x2f<<<(NN*DIM/4+255)/256,256,0,stream>>>(x, h, fflag);
  k_zero32<<<(NN+255)/256,256,0,stream>>>(counts, NN);
  k_count<<<(NE+255)/256,256,0,stream>>>(ei, iflag, counts);
  const int nbA = (NN+1023)/1024;
  k_scanA<<<nbA,1024,0,stream>>>(counts, offs, bsums);
  k_scanB<<<1,1,0,stream>>>(bsums, offs, nbA);
  k_scanC<<<(NN+255)/256,256,0,stream>>>(offs, bsums);
  k_zero32<<<(NN+255)/256,256,0,stream>>>(counts, NN);
  k_fill<<<(NE+255)/256,256,0,stream>>>(ei, iflag, offs, counts, srcs, eperm, eattr, fflag);

  for (int L=0; L<NL; ++L){
    k_gemm<<<dim3((NN+63)/64,2),256,0,stream>>>(h,
        cWlT + (size_t)L*DIM*DIM, cBl + L*DIM, gl,
        cWrT + (size_t)L*DIM*DIM, cBr + L*DIM, gr, 0, fflag);
    k_zerof<<<1,256,0,stream>>>(stats, 256);
    // attn writes into h (its input features are dead after the GEMM)
    k_attn<<<5120,256,0,stream>>>(offs, srcs, eperm,
        cWeT + (size_t)L*DIM*EDIM, cAtt + L*DIM, gl, gr, h);
    k_bnstats<<<256,256,0,stream>>>(h, stats);
    k_bnapply<<<(NN*64+255)/256,256,0,stream>>>(h, stats, cGam + L*DIM, cBet + L*DIM, h);
  }
  k_gemm<<<dim3((NN+63)/64,1),256,0,stream>>>(h, cWfT, cBf, d_out, cWfT, cBf, d_out, 1, fflag);
}

// Round 3
// 1274.745 us; speedup vs baseline: 1.2320x; 1.2320x over previous
//
#include <hip/hip_runtime.h>

#define NN 100000
#define NE 1600000
#define DIM 128
#define EDIM 16
#define NL 3

typedef unsigned short u16;
typedef unsigned int u32;
typedef __attribute__((ext_vector_type(8))) short bf16x8;
typedef __attribute__((ext_vector_type(4))) float f32x4;

__device__ __forceinline__ float b2f(u16 u){ u32 x = ((u32)u)<<16; float f; __builtin_memcpy(&f,&x,4); return f; }
__device__ __forceinline__ float b2f_lo(u32 u){ u32 x = u<<16; float f; __builtin_memcpy(&f,&x,4); return f; }
__device__ __forceinline__ float b2f_hi(u32 u){ u32 x = u & 0xffff0000u; float f; __builtin_memcpy(&f,&x,4); return f; }
__device__ __forceinline__ u16 f2b(float f){ u32 x; __builtin_memcpy(&x,&f,4); u32 r = (x + 0x7fffu + ((x>>16)&1u))>>16; return (u16)r; }
__device__ __forceinline__ float fexp2(float x){ return __builtin_amdgcn_exp2f(x); }

// DPP rotation-add within 16-lane rows: part += ror<N>(part). Pure VALU pipe (no ds_swizzle).
template<int N>
__device__ __forceinline__ float dpp_ror_add(float v){
  int x; __builtin_memcpy(&x, &v, 4);
  int y = __builtin_amdgcn_update_dpp(0, x, 0x120 | N, 0xF, 0xF, true);
  float r; __builtin_memcpy(&r, &y, 4);
  return v + r;
}

// ---------------- dtype probes ----------------
__global__ void k_probe_f(const u16* __restrict__ x, int* fflag){
  __shared__ int cnt;
  if (threadIdx.x==0) cnt = 0;
  __syncthreads();
  int sane = 0;
  for (int j=threadIdx.x; j<2048; j+=256){
    u16 w = x[j];
    int e = (w>>7)&0xFF;
    if (w==0 || (e>=100 && e<=140)) sane++;
  }
  atomicAdd(&cnt, sane);
  __syncthreads();
  if (threadIdx.x==0) *fflag = (cnt < 1900) ? 1 : 0;   // 1 => float32
}
__global__ void k_probe_i(const int* __restrict__ ei, int* iflag){
  int j = blockIdx.x*256 + threadIdx.x;
  if (j < 1024){ if (ei[2*j+1] != 0) atomicOr(iflag, 1); }  // !=0 => int32
}

// ---------------- utility ----------------
__global__ void k_zero32(int* p, int n){ int i = blockIdx.x*256 + threadIdx.x; if (i<n) p[i]=0; }
__global__ void k_zerof(float* p, int n){ int i = blockIdx.x*256 + threadIdx.x; if (i<n) p[i]=0.f; }

// canonical bf16 params; Wl/Wr/Wf stored TRANSPOSED (dst[c][k] = src[k][c])
// WET = We transposed per layer: WeT[l][c][k] = We[l][k][c]
#define SEG_WL    0
#define SEG_WR    49152
#define SEG_WE    98304
#define SEG_ATT   104448
#define SEG_GAM   104832
#define SEG_BET   105216
#define SEG_WF    105600
#define SEG_BF    121984
#define SEG_BL    122112
#define SEG_BR    122496
#define SEG_WET   122880
#define SEG_TOTAL 129024

__global__ void k_cvt_params(const void* Wl, const void* Wr, const void* We, const void* att,
                             const void* gam, const void* bet, const void* Wf, const void* bf,
                             const void* bl, const void* br,
                             u16* __restrict__ dst, const int* __restrict__ fflag){
  int i = blockIdx.x*256 + threadIdx.x;
  if (i >= SEG_TOTAL) return;
  const void* src; int off;
  if (i < SEG_WR){                       // Wl^T
    int o = i - SEG_WL; int l = o>>14, r = o&16383, c = r>>7, k = r&127;
    src = Wl; off = (l<<14)|(k<<7)|c;
  } else if (i < SEG_WE){                // Wr^T
    int o = i - SEG_WR; int l = o>>14, r = o&16383, c = r>>7, k = r&127;
    src = Wr; off = (l<<14)|(k<<7)|c;
  } else if (i < SEG_ATT){ src = We;  off = i - SEG_WE; }
  else if (i < SEG_GAM)  { src = att; off = i - SEG_ATT; }
  else if (i < SEG_BET)  { src = gam; off = i - SEG_GAM; }
  else if (i < SEG_WF)   { src = bet; off = i - SEG_BET; }
  else if (i < SEG_BF){                  // Wf^T
    int o = i - SEG_WF; int c = o>>7, k = o&127;
    src = Wf; off = (k<<7)|c;
  }
  else if (i < SEG_BL)   { src = bf;  off = i - SEG_BF; }
  else if (i < SEG_BR)   { src = bl;  off = i - SEG_BL; }
  else if (i < SEG_WET)  { src = br;  off = i - SEG_BR; }
  else {                                 // We^T: [l][c][k] <- We[l][k][c]
    int o = i - SEG_WET; int l = o>>11, r = o&2047, c = r>>4, k = r&15;
    src = We; off = (l<<11)|(k<<7)|c;
  }
  dst[i] = (*fflag) ? f2b(((const float*)src)[off]) : ((const u16*)src)[off];
}

// ---------------- CSR build ----------------
__global__ void k_count(const int* __restrict__ ei, const int* __restrict__ iflag, int* __restrict__ counts){
  int e = blockIdx.x*256 + threadIdx.x; if (e >= NE) return;
  int d;
  if (*iflag) d = ei[NE + e];
  else        d = (int)((const long long*)ei)[NE + e];
  atomicAdd(&counts[d], 1);
}
__global__ void k_scanA(const int* __restrict__ counts, int* __restrict__ offs, int* __restrict__ bsums){
  __shared__ int s[1024];
  int t = threadIdx.x; int i = blockIdx.x*1024 + t;
  int v = (i < NN) ? counts[i] : 0;
  s[t] = v; __syncthreads();
  for (int off=1; off<1024; off<<=1){
    int x = (t>=off) ? s[t-off] : 0;
    __syncthreads();
    s[t] += x;
    __syncthreads();
  }
  if (i < NN) offs[i] = s[t] - v;
  if (t == 1023) bsums[blockIdx.x] = s[1023];
}
__global__ void k_scanB(int* bsums, int* offs, int nb){
  if (threadIdx.x==0 && blockIdx.x==0){
    int run = 0;
    for (int j=0;j<nb;j++){ int tmp=bsums[j]; bsums[j]=run; run+=tmp; }
    offs[NN] = run;
  }
}
__global__ void k_scanC(int* __restrict__ offs, const int* __restrict__ bsums){
  int i = blockIdx.x*256 + threadIdx.x;
  if (i < NN) offs[i] += bsums[i>>10];
}

// fill CSR: srcs + edge_attr permuted into CSR order as bf16 (eperm)
__global__ void k_fill(const int* __restrict__ ei, const int* __restrict__ iflag,
                       const int* __restrict__ offs, int* __restrict__ counts,
                       int* __restrict__ srcs, u16* __restrict__ eperm,
                       const void* __restrict__ eattr, const int* __restrict__ fflag){
  int e = blockIdx.x*256 + threadIdx.x; if (e >= NE) return;
  int s, d;
  if (*iflag){ s = ei[e]; d = ei[NE + e]; }
  else { const long long* e64 = (const long long*)ei; s = (int)e64[e]; d = (int)e64[NE + e]; }
  int pos = offs[d] + atomicAdd(&counts[d], 1);
  srcs[pos] = s;
  uint4 lo, hi;
  if (*fflag){
    const float4* s4 = (const float4*)((const float*)eattr + (size_t)e*EDIM);
    float4 a = s4[0], b = s4[1], c = s4[2], dd = s4[3];
    lo.x = (u32)f2b(a.x) | ((u32)f2b(a.y)<<16); lo.y = (u32)f2b(a.z) | ((u32)f2b(a.w)<<16);
    lo.z = (u32)f2b(b.x) | ((u32)f2b(b.y)<<16); lo.w = (u32)f2b(b.z) | ((u32)f2b(b.w)<<16);
    hi.x = (u32)f2b(c.x) | ((u32)f2b(c.y)<<16); hi.y = (u32)f2b(c.z) | ((u32)f2b(c.w)<<16);
    hi.z = (u32)f2b(dd.x)| ((u32)f2b(dd.y)<<16);hi.w = (u32)f2b(dd.z)| ((u32)f2b(dd.w)<<16);
  } else {
    const uint4* s4 = (const uint4*)((const u16*)eattr + (size_t)e*EDIM);
    lo = s4[0]; hi = s4[1];
  }
  uint4* dst = (uint4*)(eperm + (size_t)pos*EDIM);
  dst[0] = lo; dst[1] = hi;
}

// ---------------- MFMA node GEMM with optional fused BN+leaky on the input ----------------
// out[n][c] = sum_k f(in[n][k])*W[k][c] + b[c], f = BN-affine + leaky(0.02) when st!=null.
// in_raw: read input directly (f32 or bf16 per fflag). WT = transposed weight [c][k] bf16.
#define LSTR 136   // padded LDS row stride (bf16 elems): +16B breaks bank conflicts
__global__ __launch_bounds__(256) void k_gemm(const void* __restrict__ in, int in_raw,
    const float* __restrict__ st, const u16* __restrict__ gm, const u16* __restrict__ bt,
    const u16* __restrict__ WT0, const u16* __restrict__ b0, void* __restrict__ out0,
    const u16* __restrict__ WT1, const u16* __restrict__ b1, void* __restrict__ out1,
    int store_f32, const int* __restrict__ fflag)
{
  __shared__ __align__(16) u16 Xs[64*LSTR];
  __shared__ __align__(16) u16 Ws[128*LSTR];
  __shared__ __align__(16) float sA[DIM], sB[DIM];
  const u16* WT = blockIdx.y ? WT1 : WT0;
  const u16* bi = blockIdx.y ? b1 : b0;
  void* out     = blockIdx.y ? out1 : out0;
  int t = threadIdx.x;
  int n0 = blockIdx.x*64;
  // stage W^T (128x128 bf16 = 2048 uint4), coalesced
  const uint4* w4 = (const uint4*)WT;
  for (int p = t; p < 2048; p += 256){
    int c = p >> 4, k16 = p & 15;
    *(uint4*)&Ws[c*LSTR + k16*8] = w4[p];
  }
  // BN affine coefficients: y = v*A[c] + B[c]
  if (st && t < DIM){
    const float invN = 1.f/(float)NN;
    float mu = st[t]*invN;
    float va = st[DIM+t]*invN - mu*mu;
    float rs = rsqrtf(fmaxf(va, 0.f) + 1e-5f);
    float A = rs*b2f(gm[t]);
    sA[t] = A;
    sB[t] = b2f(bt[t]) - mu*A;
  }
  __syncthreads();
  // stage X (64x128 -> bf16), optional BN+leaky
  for (int p = t; p < 2048; p += 256){
    int r = p >> 5, c4 = p & 31;
    int n = n0 + r;
    uint2 pk = make_uint2(0,0);
    if (n < NN){
      if (in_raw && !(*fflag)){
        pk = *(const uint2*)((const u16*)in + (size_t)n*DIM + c4*4);
      } else {
        float4 v = *(const float4*)((const float*)in + (size_t)n*DIM + c4*4);
        if (st){
          int c = c4*4;
          float4 Af = *(const float4*)&sA[c];
          float4 Bf = *(const float4*)&sB[c];
          v.x = v.x*Af.x + Bf.x; v.x = fmaxf(v.x, 0.02f*v.x);
          v.y = v.y*Af.y + Bf.y; v.y = fmaxf(v.y, 0.02f*v.y);
          v.z = v.z*Af.z + Bf.z; v.z = fmaxf(v.z, 0.02f*v.z);
          v.w = v.w*Af.w + Bf.w; v.w = fmaxf(v.w, 0.02f*v.w);
        }
        pk.x = (u32)f2b(v.x) | ((u32)f2b(v.y)<<16);
        pk.y = (u32)f2b(v.z) | ((u32)f2b(v.w)<<16);
      }
    }
    *(uint2*)&Xs[r*LSTR + c4*4] = pk;
  }
  __syncthreads();
  int lane = t & 63, wv = t >> 6;
  int m = lane & 15, q = lane >> 4;
  f32x4 acc[8];
  #pragma unroll
  for (int i=0;i<8;i++) acc[i] = (f32x4){0.f,0.f,0.f,0.f};
  #pragma unroll
  for (int ks=0; ks<4; ks++){
    bf16x8 af = *(const bf16x8*)&Xs[(wv*16 + m)*LSTR + ks*32 + q*8];
    #pragma unroll
    for (int nt=0; nt<8; nt++){
      bf16x8 bfr = *(const bf16x8*)&Ws[(nt*16 + m)*LSTR + ks*32 + q*8];
      acc[nt] = __builtin_amdgcn_mfma_f32_16x16x32_bf16(af, bfr, acc[nt], 0, 0, 0);
    }
  }
  bool f32out = store_f32 && (*fflag);
  #pragma unroll
  for (int nt=0; nt<8; nt++){
    int col = nt*16 + m;
    float bvv = b2f(bi[col]);
    #pragma unroll
    for (int r=0;r<4;r++){
      int row = n0 + wv*16 + q*4 + r;
      if (row < NN){
        float val = acc[nt][r] + bvv;
        if (f32out) ((float*)out)[(size_t)row*DIM + col] = val;
        else        ((u16*)out)[(size_t)row*DIM + col] = f2b(val);
      }
    }
  }
}

// ---------------- attention ----------------
// One wave per node (grid-stride). Per 16-edge CSR tile, el = eperm_tile @ We on the
// matrix pipe (A = [16e x 16k] zero-padded to K=32, B = We^T fragments from the
// pre-transposed global segment). Next tile's A-fragment is prefetched during consume.
// D scattered into a per-wave padded LDS tile [16][ELP] f32, consumed by the
// straight-line online-softmax loop (DPP rotation reduce, exp2-domain logits).
#define ELP 132  // el row stride (f32): 528B/row -> 2-way bank aliasing on write (free)
__global__ __launch_bounds__(256,4) void k_attn(const int* __restrict__ offs, const int* __restrict__ srcs,
    const u16* __restrict__ eperm, const u16* __restrict__ WeT, const u16* __restrict__ att,
    const u16* __restrict__ gl, const u16* __restrict__ gr, float* __restrict__ agg)
{
  __shared__ __align__(16) float sEl[4][16*ELP];   // per-wave el tiles, 33.8 KB
  int t = threadIdx.x;
  int lane = t & 63, wv = t >> 6;
  int m = lane & 15, q = lane >> 4;
  // loop-invariant B fragments of We^T: bwe[tc] holds WeT[tc*16+m][q*8..q*8+7] (zero for k>=16)
  bf16x8 bwe[8];
  #pragma unroll
  for (int tc = 0; tc < 8; ++tc){
    if (q < 2) bwe[tc] = *(const bf16x8*)&WeT[(tc*16 + m)*16 + q*8];
    else       bwe[tc] = (bf16x8){0,0,0,0,0,0,0,0};
  }
  // fold log2(e) into att so exponentials are native exp2 (alpha mathematically identical)
  const float LOG2E = 1.442695041f;
  float att0 = b2f(att[2*lane])*LOG2E, att1 = b2f(att[2*lane+1])*LOG2E;
  float* el = &sEl[wv][0];
  const u32* glv = (const u32*)gl;

  for (int node = blockIdx.x*4 + wv; node < NN; node += gridDim.x*4){
    u32 g = ((const u32*)gr)[(size_t)node*64 + lane];
    float gr0 = b2f_lo(g), gr1 = b2f_hi(g);
    float ms[4], ds[4], o0[4], o1[4];
    #pragma unroll
    for (int i=0;i<4;i++){ ms[i] = -INFINITY; ds[i]=0.f; o0[i]=0.f; o1[i]=0.f; }
    int beg = offs[node], end = offs[node+1];
    // prefetch first tile's A-fragment
    bf16x8 af = (bf16x8){0,0,0,0,0,0,0,0};
    if (q < 2 && beg < end){
      int eidx = beg + m; eidx = eidx < NE ? eidx : NE-1;
      af = *(const bf16x8*)&eperm[(size_t)eidx*EDIM + q*8];
    }
    for (int tb = beg; tb < end; tb += 16){
      // ---- el tile on matrix pipe ----
      #pragma unroll
      for (int tc = 0; tc < 8; ++tc){
        f32x4 d = __builtin_amdgcn_mfma_f32_16x16x32_bf16(af, bwe[tc], (f32x4){0.f,0.f,0.f,0.f}, 0, 0, 0);
        #pragma unroll
        for (int r = 0; r < 4; ++r)
          el[(q*4 + r)*ELP + tc*16 + m] = d[r];     // edge=q*4+r, ch=tc*16+m
      }
      // prefetch NEXT tile's A-fragment (hides eperm latency under consume)
      if (q < 2){
        int eidx = tb + 16 + m; eidx = eidx < NE ? eidx : NE-1;
        af = *(const bf16x8*)&eperm[(size_t)eidx*EDIM + q*8];
      }
      // same-wave LDS write->read: in-order DS pipe + compiler lgkmcnt, no barrier needed
      int tend = end < tb + 16 ? end : tb + 16;
      int e = tb;
      for (; e + 4 <= tend; e += 4){
        int sidx[4];
        #pragma unroll
        for (int i=0;i<4;i++) sidx[i] = srcs[e+i];
        u32 gx[4];
        #pragma unroll
        for (int i=0;i<4;i++) gx[i] = glv[((u32)sidx[i]<<6) | (u32)lane];
        float2 ev[4];
        #pragma unroll
        for (int i=0;i<4;i++) ev[i] = *(const float2*)&el[(e - tb + i)*ELP + 2*lane];
        #pragma unroll
        for (int i=0;i<4;i++){
          float xj0 = b2f_lo(gx[i]), xj1 = b2f_hi(gx[i]);
          float e0 = xj0 + gr0 + ev[i].x;
          float e1 = xj1 + gr1 + ev[i].y;
          e0 = fmaxf(e0, 0.2f*e0);
          e1 = fmaxf(e1, 0.2f*e1);
          float part = e0*att0 + e1*att1;          // log2-domain logit
          part = dpp_ror_add<1>(part);
          part = dpp_ror_add<2>(part);
          part = dpp_ror_add<4>(part);
          part = dpp_ror_add<8>(part);
          float nm = fmaxf(ms[i], part);
          float sc = fexp2(ms[i] - nm);            // -inf -> 0 on first edge
          float pp = fexp2(part - nm);
          ds[i] = ds[i]*sc + pp;
          o0[i] = o0[i]*sc + pp*xj0;
          o1[i] = o1[i]*sc + pp*xj1;
          ms[i] = nm;
        }
      }
      for (; e < tend; ++e){
        int s = srcs[e];
        u32 gx = glv[((u32)s<<6) | (u32)lane];
        float2 ev = *(const float2*)&el[(e - tb)*ELP + 2*lane];
        float xj0 = b2f_lo(gx), xj1 = b2f_hi(gx);
        float e0 = xj0 + gr0 + ev.x;
        float e1 = xj1 + gr1 + ev.y;
        e0 = fmaxf(e0, 0.2f*e0);
        e1 = fmaxf(e1, 0.2f*e1);
        float part = e0*att0 + e1*att1;
        part = dpp_ror_add<1>(part);
        part = dpp_ror_add<2>(part);
        part = dpp_ror_add<4>(part);
        part = dpp_ror_add<8>(part);
        float nm = fmaxf(ms[0], part);
        float sc = fexp2(ms[0] - nm);
        float pp = fexp2(part - nm);
        ds[0] = ds[0]*sc + pp;
        o0[0] = o0[0]*sc + pp*xj0;
        o1[0] = o1[0]*sc + pp*xj1;
        ms[0] = nm;
      }
    }
    // merge states (guard -inf: empty state contributes 0)
    float M = fmaxf(fmaxf(ms[0],ms[1]), fmaxf(ms[2],ms[3]));
    float D = 0.f, P0 = 0.f, P1 = 0.f;
    #pragma unroll
    for (int i=0;i<4;i++){
      if (ms[i] != -INFINITY){
        float sc = fexp2(ms[i] - M);
        D += sc*ds[i]; P0 += sc*o0[i]; P1 += sc*o1[i];
      }
    }
    float inv = 1.f/(D + 1e-16f);
    ((float2*)agg)[(size_t)node*64 + lane] = make_float2(P0*inv, P1*inv);
  }
}

// ---------------- batch norm stats (BN apply is fused into the next k_gemm) ----------------
__global__ __launch_bounds__(256) void k_bnstats(const float* __restrict__ agg, float* __restrict__ stats){
  int t = threadIdx.x;
  int p = t & 63;
  int rg = t >> 6;
  float s0=0,s1=0,q0=0,q1=0;
  for (int r = blockIdx.x*4 + rg; r < NN; r += 256*4){
    float2 v = ((const float2*)agg)[(size_t)r*64 + p];
    s0 += v.x; s1 += v.y; q0 += v.x*v.x; q1 += v.y*v.y;
  }
  int c0 = 2*p;
  atomicAdd(&stats[c0],     s0); atomicAdd(&stats[c0+1],     s1);
  atomicAdd(&stats[DIM+c0], q0); atomicAdd(&stats[DIM+c0+1], q1);
}

// ---------------- launch ----------------
extern "C" void kernel_launch(void* const* d_in, const int* in_sizes, int n_in,
                              void* d_out, int out_size, void* d_ws, size_t ws_size,
                              hipStream_t stream){
  (void)in_sizes; (void)n_in; (void)out_size; (void)ws_size;
  const void* x    = d_in[0];
  const int* ei    = (const int*)d_in[1];
  const void* eattr= d_in[2];
  // d_in[9] = conv bias: cancels under BN mean-subtraction, skipped
  char* p = (char*)d_ws;
  auto alloc = [&](size_t b)->void*{ void* q = p; p += (b + 255) & ~(size_t)255; return q; };
  float* h      = (float*)alloc((size_t)NN*DIM*4);    // attn output (raw agg); BN fused downstream
  u16*   gl     = (u16*)  alloc((size_t)NN*DIM*2);
  u16*   gr     = (u16*)  alloc((size_t)NN*DIM*2);
  int*   offs   = (int*)  alloc((size_t)(NN+1)*4);
  int*   counts = (int*)  alloc((size_t)NN*4);
  int*   srcs   = (int*)  alloc((size_t)NE*4);
  u16*   eperm  = (u16*)  alloc((size_t)NE*EDIM*2);   // edge_attr in CSR order, bf16
  float* stats  = (float*)alloc(256*4);
  int*   bsums  = (int*)  alloc(128*4);
  int*   flags  = (int*)  alloc(8);                   // [0]=fflag, [1]=iflag
  u16*   cpar   = (u16*)  alloc((size_t)SEG_TOTAL*2);

  int* fflag = flags;
  int* iflag = flags + 1;

  k_zero32<<<1,256,0,stream>>>(flags, 2);
  k_probe_f<<<1,256,0,stream>>>((const u16*)x, fflag);
  k_probe_i<<<4,256,0,stream>>>(ei, iflag);
  k_cvt_params<<<(SEG_TOTAL+255)/256,256,0,stream>>>(d_in[3], d_in[5], d_in[7], d_in[8],
      d_in[10], d_in[11], d_in[12], d_in[13], d_in[4], d_in[6], cpar, fflag);
  const u16* cWlT= cpar + SEG_WL;  const u16* cWrT= cpar + SEG_WR;
  const u16* cAtt= cpar + SEG_ATT;
  const u16* cGam= cpar + SEG_GAM; const u16* cBet= cpar + SEG_BET;
  const u16* cWfT= cpar + SEG_WF;  const u16* cBf = cpar + SEG_BF;
  const u16* cBl = cpar + SEG_BL;  const u16* cBr = cpar + SEG_BR;
  const u16* cWeT= cpar + SEG_WET;

  k_zero32<<<(NN+255)/256,256,0,stream>>>(counts, NN);
  k_count<<<(NE+255)/256,256,0,stream>>>(ei, iflag, counts);
  const int nbA = (NN+1023)/1024;
  k_scanA<<<nbA,1024,0,stream>>>(counts, offs, bsums);
  k_scanB<<<1,1,0,stream>>>(bsums, offs, nbA);
  k_scanC<<<(NN+255)/256,256,0,stream>>>(offs, bsums);
  k_zero32<<<(NN+255)/256,256,0,stream>>>(counts, NN);
  k_fill<<<(NE+255)/256,256,0,stream>>>(ei, iflag, offs, counts, srcs, eperm, eattr, fflag);

  for (int L=0; L<NL; ++L){
    if (L == 0)
      k_gemm<<<dim3((NN+63)/64,2),256,0,stream>>>(x, 1, nullptr, nullptr, nullptr,
          cWlT + (size_t)L*DIM*DIM, cBl + L*DIM, gl,
          cWrT + (size_t)L*DIM*DIM, cBr + L*DIM, gr, 0, fflag);
    else
      k_gemm<<<dim3((NN+63)/64,2),256,0,stream>>>(h, 0, stats, cGam + (L-1)*DIM, cBet + (L-1)*DIM,
          cWlT + (size_t)L*DIM*DIM, cBl + L*DIM, gl,
          cWrT + (size_t)L*DIM*DIM, cBr + L*DIM, gr, 0, fflag);
    k_zerof<<<1,256,0,stream>>>(stats, 256);
    // attn writes raw agg into h (its input features are dead after the GEMM)
    k_attn<<<2048,256,0,stream>>>(offs, srcs, eperm,
        cWeT + (size_t)L*DIM*EDIM, cAtt + L*DIM, gl, gr, h);
    k_bnstats<<<256,256,0,stream>>>(h, stats);
  }
  // final projection with BN(layer2)+leaky fused on the input
  k_gemm<<<dim3((NN+63)/64,1),256,0,stream>>>(h, 0, stats, cGam + 2*DIM, cBet + 2*DIM,
      cWfT, cBf, d_out, cWfT, cBf, d_out, 1, fflag);
}

// Round 5
// 1173.594 us; speedup vs baseline: 1.3382x; 1.0862x over previous
//
#include <hip/hip_runtime.h>

#define NN 100000
#define NE 1600000
#define DIM 128
#define EDIM 16
#define NL 3

typedef unsigned short u16;
typedef unsigned int u32;
typedef __attribute__((ext_vector_type(8))) short bf16x8;
typedef __attribute__((ext_vector_type(4))) float f32x4;

__device__ __forceinline__ float b2f(u16 u){ u32 x = ((u32)u)<<16; float f; __builtin_memcpy(&f,&x,4); return f; }
__device__ __forceinline__ float b2f_lo(u32 u){ u32 x = u<<16; float f; __builtin_memcpy(&f,&x,4); return f; }
__device__ __forceinline__ float b2f_hi(u32 u){ u32 x = u & 0xffff0000u; float f; __builtin_memcpy(&f,&x,4); return f; }
__device__ __forceinline__ u16 f2b(float f){ u32 x; __builtin_memcpy(&x,&f,4); u32 r = (x + 0x7fffu + ((x>>16)&1u))>>16; return (u16)r; }
__device__ __forceinline__ float fexp2(float x){ return __builtin_amdgcn_exp2f(x); }

// DPP rotation-add within 16-lane rows: part += ror<N>(part).
// NOTE: must stay a builtin (NOT inline asm) — the compiler inserts the required
// VALU-write -> DPP-read hazard s_nops; raw asm skips them (round-4 failure).
template<int N>
__device__ __forceinline__ float dpp_ror_add(float v){
  int x; __builtin_memcpy(&x, &v, 4);
  int y = __builtin_amdgcn_update_dpp(0, x, 0x120 | N, 0xF, 0xF, true);
  float r; __builtin_memcpy(&r, &y, 4);
  return v + r;
}

// ---------------- dtype probes ----------------
__global__ void k_probe_f(const u16* __restrict__ x, int* fflag){
  __shared__ int cnt;
  if (threadIdx.x==0) cnt = 0;
  __syncthreads();
  int sane = 0;
  for (int j=threadIdx.x; j<2048; j+=256){
    u16 w = x[j];
    int e = (w>>7)&0xFF;
    if (w==0 || (e>=100 && e<=140)) sane++;
  }
  atomicAdd(&cnt, sane);
  __syncthreads();
  if (threadIdx.x==0) *fflag = (cnt < 1900) ? 1 : 0;   // 1 => float32
}
__global__ void k_probe_i(const int* __restrict__ ei, int* iflag){
  int j = blockIdx.x*256 + threadIdx.x;
  if (j < 1024){ if (ei[2*j+1] != 0) atomicOr(iflag, 1); }  // !=0 => int32
}

// ---------------- utility ----------------
__global__ void k_zero32(int* p, int n){ int i = blockIdx.x*256 + threadIdx.x; if (i<n) p[i]=0; }
__global__ void k_zerof(float* p, int n){ int i = blockIdx.x*256 + threadIdx.x; if (i<n) p[i]=0.f; }

// canonical bf16 params; Wl/Wr/Wf stored TRANSPOSED (dst[c][k] = src[k][c])
// WET = We transposed per layer: WeT[l][c][k] = We[l][k][c]
#define SEG_WL    0
#define SEG_WR    49152
#define SEG_WE    98304
#define SEG_ATT   104448
#define SEG_GAM   104832
#define SEG_BET   105216
#define SEG_WF    105600
#define SEG_BF    121984
#define SEG_BL    122112
#define SEG_BR    122496
#define SEG_WET   122880
#define SEG_TOTAL 129024

__global__ void k_cvt_params(const void* Wl, const void* Wr, const void* We, const void* att,
                             const void* gam, const void* bet, const void* Wf, const void* bf,
                             const void* bl, const void* br,
                             u16* __restrict__ dst, const int* __restrict__ fflag){
  int i = blockIdx.x*256 + threadIdx.x;
  if (i >= SEG_TOTAL) return;
  const void* src; int off;
  if (i < SEG_WR){                       // Wl^T
    int o = i - SEG_WL; int l = o>>14, r = o&16383, c = r>>7, k = r&127;
    src = Wl; off = (l<<14)|(k<<7)|c;
  } else if (i < SEG_WE){                // Wr^T
    int o = i - SEG_WR; int l = o>>14, r = o&16383, c = r>>7, k = r&127;
    src = Wr; off = (l<<14)|(k<<7)|c;
  } else if (i < SEG_ATT){ src = We;  off = i - SEG_WE; }
  else if (i < SEG_GAM)  { src = att; off = i - SEG_ATT; }
  else if (i < SEG_BET)  { src = gam; off = i - SEG_GAM; }
  else if (i < SEG_WF)   { src = bet; off = i - SEG_BET; }
  else if (i < SEG_BF){                  // Wf^T
    int o = i - SEG_WF; int c = o>>7, k = o&127;
    src = Wf; off = (k<<7)|c;
  }
  else if (i < SEG_BL)   { src = bf;  off = i - SEG_BF; }
  else if (i < SEG_BR)   { src = bl;  off = i - SEG_BL; }
  else if (i < SEG_WET)  { src = br;  off = i - SEG_BR; }
  else {                                 // We^T: [l][c][k] <- We[l][k][c]
    int o = i - SEG_WET; int l = o>>11, r = o&2047, c = r>>4, k = r&15;
    src = We; off = (l<<11)|(k<<7)|c;
  }
  dst[i] = (*fflag) ? f2b(((const float*)src)[off]) : ((const u16*)src)[off];
}

// ---------------- CSR build ----------------
__global__ void k_count(const int* __restrict__ ei, const int* __restrict__ iflag, int* __restrict__ counts){
  int e = blockIdx.x*256 + threadIdx.x; if (e >= NE) return;
  int d;
  if (*iflag) d = ei[NE + e];
  else        d = (int)((const long long*)ei)[NE + e];
  atomicAdd(&counts[d], 1);
}
__global__ void k_scanA(const int* __restrict__ counts, int* __restrict__ offs, int* __restrict__ bsums){
  __shared__ int s[1024];
  int t = threadIdx.x; int i = blockIdx.x*1024 + t;
  int v = (i < NN) ? counts[i] : 0;
  s[t] = v; __syncthreads();
  for (int off=1; off<1024; off<<=1){
    int x = (t>=off) ? s[t-off] : 0;
    __syncthreads();
    s[t] += x;
    __syncthreads();
  }
  if (i < NN) offs[i] = s[t] - v;
  if (t == 1023) bsums[blockIdx.x] = s[1023];
}
__global__ void k_scanB(int* bsums, int* offs, int nb){
  if (threadIdx.x==0 && blockIdx.x==0){
    int run = 0;
    for (int j=0;j<nb;j++){ int tmp=bsums[j]; bsums[j]=run; run+=tmp; }
    offs[NN] = run;
  }
}
__global__ void k_scanC(int* __restrict__ offs, const int* __restrict__ bsums){
  int i = blockIdx.x*256 + threadIdx.x;
  if (i < NN) offs[i] += bsums[i>>10];
}

// fill CSR: srcs + edge_attr permuted into CSR order as bf16 (eperm)
__global__ void k_fill(const int* __restrict__ ei, const int* __restrict__ iflag,
                       const int* __restrict__ offs, int* __restrict__ counts,
                       int* __restrict__ srcs, u16* __restrict__ eperm,
                       const void* __restrict__ eattr, const int* __restrict__ fflag){
  int e = blockIdx.x*256 + threadIdx.x; if (e >= NE) return;
  int s, d;
  if (*iflag){ s = ei[e]; d = ei[NE + e]; }
  else { const long long* e64 = (const long long*)ei; s = (int)e64[e]; d = (int)e64[NE + e]; }
  int pos = offs[d] + atomicAdd(&counts[d], 1);
  srcs[pos] = s;
  uint4 lo, hi;
  if (*fflag){
    const float4* s4 = (const float4*)((const float*)eattr + (size_t)e*EDIM);
    float4 a = s4[0], b = s4[1], c = s4[2], dd = s4[3];
    lo.x = (u32)f2b(a.x) | ((u32)f2b(a.y)<<16); lo.y = (u32)f2b(a.z) | ((u32)f2b(a.w)<<16);
    lo.z = (u32)f2b(b.x) | ((u32)f2b(b.y)<<16); lo.w = (u32)f2b(b.z) | ((u32)f2b(b.w)<<16);
    hi.x = (u32)f2b(c.x) | ((u32)f2b(c.y)<<16); hi.y = (u32)f2b(c.z) | ((u32)f2b(c.w)<<16);
    hi.z = (u32)f2b(dd.x)| ((u32)f2b(dd.y)<<16);hi.w = (u32)f2b(dd.z)| ((u32)f2b(dd.w)<<16);
  } else {
    const uint4* s4 = (const uint4*)((const u16*)eattr + (size_t)e*EDIM);
    lo = s4[0]; hi = s4[1];
  }
  uint4* dst = (uint4*)(eperm + (size_t)pos*EDIM);
  dst[0] = lo; dst[1] = hi;
}

// ---------------- MFMA node GEMM with optional fused BN+leaky on the input ----------------
// out[n][c] = sum_k f(in[n][k])*W[k][c] + b[c], f = BN-affine + leaky(0.02) when st!=null.
// in_raw: read input directly (f32 or bf16 per fflag). WT = transposed weight [c][k] bf16.
#define LSTR 136   // padded LDS row stride (bf16 elems): +16B breaks bank conflicts
__global__ __launch_bounds__(256) void k_gemm(const void* __restrict__ in, int in_raw,
    const float* __restrict__ st, const u16* __restrict__ gm, const u16* __restrict__ bt,
    const u16* __restrict__ WT0, const u16* __restrict__ b0, void* __restrict__ out0,
    const u16* __restrict__ WT1, const u16* __restrict__ b1, void* __restrict__ out1,
    int store_f32, const int* __restrict__ fflag)
{
  __shared__ __align__(16) u16 Xs[64*LSTR];
  __shared__ __align__(16) u16 Ws[128*LSTR];
  __shared__ __align__(16) float sA[DIM], sB[DIM];
  const u16* WT = blockIdx.y ? WT1 : WT0;
  const u16* bi = blockIdx.y ? b1 : b0;
  void* out     = blockIdx.y ? out1 : out0;
  int t = threadIdx.x;
  int n0 = blockIdx.x*64;
  // stage W^T (128x128 bf16 = 2048 uint4), coalesced
  const uint4* w4 = (const uint4*)WT;
  for (int p = t; p < 2048; p += 256){
    int c = p >> 4, k16 = p & 15;
    *(uint4*)&Ws[c*LSTR + k16*8] = w4[p];
  }
  // BN affine coefficients: y = v*A[c] + B[c]
  if (st && t < DIM){
    const float invN = 1.f/(float)NN;
    float mu = st[t]*invN;
    float va = st[DIM+t]*invN - mu*mu;
    float rs = rsqrtf(fmaxf(va, 0.f) + 1e-5f);
    float A = rs*b2f(gm[t]);
    sA[t] = A;
    sB[t] = b2f(bt[t]) - mu*A;
  }
  __syncthreads();
  // stage X (64x128 -> bf16), optional BN+leaky
  for (int p = t; p < 2048; p += 256){
    int r = p >> 5, c4 = p & 31;
    int n = n0 + r;
    uint2 pk = make_uint2(0,0);
    if (n < NN){
      if (in_raw && !(*fflag)){
        pk = *(const uint2*)((const u16*)in + (size_t)n*DIM + c4*4);
      } else {
        float4 v = *(const float4*)((const float*)in + (size_t)n*DIM + c4*4);
        if (st){
          int c = c4*4;
          float4 Af = *(const float4*)&sA[c];
          float4 Bf = *(const float4*)&sB[c];
          v.x = v.x*Af.x + Bf.x; v.x = fmaxf(v.x, 0.02f*v.x);
          v.y = v.y*Af.y + Bf.y; v.y = fmaxf(v.y, 0.02f*v.y);
          v.z = v.z*Af.z + Bf.z; v.z = fmaxf(v.z, 0.02f*v.z);
          v.w = v.w*Af.w + Bf.w; v.w = fmaxf(v.w, 0.02f*v.w);
        }
        pk.x = (u32)f2b(v.x) | ((u32)f2b(v.y)<<16);
        pk.y = (u32)f2b(v.z) | ((u32)f2b(v.w)<<16);
      }
    }
    *(uint2*)&Xs[r*LSTR + c4*4] = pk;
  }
  __syncthreads();
  int lane = t & 63, wv = t >> 6;
  int m = lane & 15, q = lane >> 4;
  f32x4 acc[8];
  #pragma unroll
  for (int i=0;i<8;i++) acc[i] = (f32x4){0.f,0.f,0.f,0.f};
  #pragma unroll
  for (int ks=0; ks<4; ks++){
    bf16x8 af = *(const bf16x8*)&Xs[(wv*16 + m)*LSTR + ks*32 + q*8];
    #pragma unroll
    for (int nt=0; nt<8; nt++){
      bf16x8 bfr = *(const bf16x8*)&Ws[(nt*16 + m)*LSTR + ks*32 + q*8];
      acc[nt] = __builtin_amdgcn_mfma_f32_16x16x32_bf16(af, bfr, acc[nt], 0, 0, 0);
    }
  }
  bool f32out = store_f32 && (*fflag);
  #pragma unroll
  for (int nt=0; nt<8; nt++){
    int col = nt*16 + m;
    float bvv = b2f(bi[col]);
    #pragma unroll
    for (int r=0;r<4;r++){
      int row = n0 + wv*16 + q*4 + r;
      if (row < NN){
        float val = acc[nt][r] + bvv;
        if (f32out) ((float*)out)[(size_t)row*DIM + col] = val;
        else        ((u16*)out)[(size_t)row*DIM + col] = f2b(val);
      }
    }
  }
}

// ---------------- attention (+ fused BN-stats) ----------------
// One wave per node (grid-stride). Per 16-edge CSR tile, el = eperm_tile @ We on the
// matrix pipe with SWAPPED operands: mfma(bwe[tc], af) -> D[ch][edge], so each lane's
// 4 D-regs are 4 consecutive channels of ONE edge row -> single ds_write_b128 per tc
// into el[edge][ELP]. Read side identical to the verified round-3 code. Online softmax
// with builtin-DPP rotation reduce; BN stats accumulated in registers and atomically
// merged per block at the end (bnstats kernel eliminated).
#define ELP 132  // el row stride (f32): write b128 bank-quads spread 8-way, read 2-way (free)
__global__ __launch_bounds__(256,4) void k_attn(const int* __restrict__ offs, const int* __restrict__ srcs,
    const u16* __restrict__ eperm, const u16* __restrict__ WeT, const u16* __restrict__ att,
    const u16* __restrict__ gl, const u16* __restrict__ gr, float* __restrict__ agg,
    float* __restrict__ stats)
{
  __shared__ __align__(16) float sEl[4][16*ELP];   // per-wave el tiles, 33.8 KB
  int t = threadIdx.x;
  int lane = t & 63, wv = t >> 6;
  int m = lane & 15, q = lane >> 4;
  // loop-invariant fragments of We^T: bwe[tc] holds WeT[tc*16+m][q*8..q*8+7] (zero for k>=16)
  bf16x8 bwe[8];
  #pragma unroll
  for (int tc = 0; tc < 8; ++tc){
    if (q < 2) bwe[tc] = *(const bf16x8*)&WeT[(tc*16 + m)*16 + q*8];
    else       bwe[tc] = (bf16x8){0,0,0,0,0,0,0,0};
  }
  // fold log2(e) into att so exponentials are native exp2 (alpha mathematically identical)
  const float LOG2E = 1.442695041f;
  float att0 = b2f(att[2*lane])*LOG2E, att1 = b2f(att[2*lane+1])*LOG2E;
  float* el = &sEl[wv][0];
  const u32* glv = (const u32*)gl + lane;   // lane folded into base
  float s0=0.f, s1=0.f, sq0=0.f, sq1=0.f;   // BN-stats accumulators (lane owns chs 2l,2l+1)

  for (int node = blockIdx.x*4 + wv; node < NN; node += gridDim.x*4){
    u32 g = ((const u32*)gr)[(size_t)node*64 + lane];
    float gr0 = b2f_lo(g), gr1 = b2f_hi(g);
    float ms[4], ds[4], o0[4], o1[4];
    #pragma unroll
    for (int i=0;i<4;i++){ ms[i] = -INFINITY; ds[i]=0.f; o0[i]=0.f; o1[i]=0.f; }
    int beg = offs[node], end = offs[node+1];
    // prefetch first tile's A-fragment
    bf16x8 af = (bf16x8){0,0,0,0,0,0,0,0};
    if (q < 2 && beg < end){
      int eidx = beg + m; eidx = eidx < NE ? eidx : NE-1;
      af = *(const bf16x8*)&eperm[(size_t)eidx*EDIM + q*8];
    }
    for (int tb = beg; tb < end; tb += 16){
      // ---- el tile on matrix pipe; D[ch][edge] -> vectorized b128 scatter ----
      #pragma unroll
      for (int tc = 0; tc < 8; ++tc){
        f32x4 d = __builtin_amdgcn_mfma_f32_16x16x32_bf16(bwe[tc], af, (f32x4){0.f,0.f,0.f,0.f}, 0, 0, 0);
        *(f32x4*)&el[m*ELP + tc*16 + q*4] = d;   // edge=m, ch=tc*16+q*4..+3
      }
      // prefetch NEXT tile's A-fragment (hides eperm latency under consume)
      if (q < 2){
        int eidx = tb + 16 + m; eidx = eidx < NE ? eidx : NE-1;
        af = *(const bf16x8*)&eperm[(size_t)eidx*EDIM + q*8];
      }
      // same-wave LDS write->read: in-order DS pipe + compiler lgkmcnt, no barrier needed
      int tend = end < tb + 16 ? end : tb + 16;
      int e = tb;
      for (; e + 4 <= tend; e += 4){
        int sidx[4];
        #pragma unroll
        for (int i=0;i<4;i++) sidx[i] = srcs[e+i];
        u32 gx[4];
        #pragma unroll
        for (int i=0;i<4;i++) gx[i] = glv[(u32)sidx[i]<<6];
        float2 ev[4];
        #pragma unroll
        for (int i=0;i<4;i++) ev[i] = *(const float2*)&el[(e - tb + i)*ELP + 2*lane];
        #pragma unroll
        for (int i=0;i<4;i++){
          float xj0 = b2f_lo(gx[i]), xj1 = b2f_hi(gx[i]);
          float e0 = xj0 + gr0 + ev[i].x;
          float e1 = xj1 + gr1 + ev[i].y;
          e0 = fmaxf(e0, 0.2f*e0);
          e1 = fmaxf(e1, 0.2f*e1);
          float part = e0*att0 + e1*att1;          // log2-domain logit
          part = dpp_ror_add<1>(part);
          part = dpp_ror_add<2>(part);
          part = dpp_ror_add<4>(part);
          part = dpp_ror_add<8>(part);
          float nm = fmaxf(ms[i], part);
          float sc = fexp2(ms[i] - nm);            // -inf -> 0 on first edge
          float pp = fexp2(part - nm);
          ds[i] = ds[i]*sc + pp;
          o0[i] = o0[i]*sc + pp*xj0;
          o1[i] = o1[i]*sc + pp*xj1;
          ms[i] = nm;
        }
      }
      for (; e < tend; ++e){
        int s = srcs[e];
        u32 gx = glv[(u32)s<<6];
        float2 ev = *(const float2*)&el[(e - tb)*ELP + 2*lane];
        float xj0 = b2f_lo(gx), xj1 = b2f_hi(gx);
        float e0 = xj0 + gr0 + ev.x;
        float e1 = xj1 + gr1 + ev.y;
        e0 = fmaxf(e0, 0.2f*e0);
        e1 = fmaxf(e1, 0.2f*e1);
        float part = e0*att0 + e1*att1;
        part = dpp_ror_add<1>(part);
        part = dpp_ror_add<2>(part);
        part = dpp_ror_add<4>(part);
        part = dpp_ror_add<8>(part);
        float nm = fmaxf(ms[0], part);
        float sc = fexp2(ms[0] - nm);
        float pp = fexp2(part - nm);
        ds[0] = ds[0]*sc + pp;
        o0[0] = o0[0]*sc + pp*xj0;
        o1[0] = o1[0]*sc + pp*xj1;
        ms[0] = nm;
      }
    }
    // merge states (guard -inf: empty state contributes 0)
    float M = fmaxf(fmaxf(ms[0],ms[1]), fmaxf(ms[2],ms[3]));
    float D = 0.f, P0 = 0.f, P1 = 0.f;
    #pragma unroll
    for (int i=0;i<4;i++){
      if (ms[i] != -INFINITY){
        float sc = fexp2(ms[i] - M);
        D += sc*ds[i]; P0 += sc*o0[i]; P1 += sc*o1[i];
      }
    }
    float inv = 1.f/(D + 1e-16f);
    float v0 = P0*inv, v1 = P1*inv;
    s0 += v0; s1 += v1; sq0 += v0*v0; sq1 += v1*v1;
    ((float2*)agg)[(size_t)node*64 + lane] = make_float2(v0, v1);
  }
  // ---- block-reduce BN stats (sEl is dead; each wave writes only its own slice) ----
  {
    float* sp = &sEl[wv][0];
    sp[lane*4+0]=s0; sp[lane*4+1]=s1; sp[lane*4+2]=sq0; sp[lane*4+3]=sq1;
    __syncthreads();
    if (wv == 0){
      float a0=0,a1=0,b0=0,b1=0;
      #pragma unroll
      for (int w=0; w<4; ++w){
        a0 += sEl[w][lane*4+0]; a1 += sEl[w][lane*4+1];
        b0 += sEl[w][lane*4+2]; b1 += sEl[w][lane*4+3];
      }
      int c0 = 2*lane;
      atomicAdd(&stats[c0],     a0); atomicAdd(&stats[c0+1],     a1);
      atomicAdd(&stats[DIM+c0], b0); atomicAdd(&stats[DIM+c0+1], b1);
    }
  }
}

// ---------------- launch ----------------
extern "C" void kernel_launch(void* const* d_in, const int* in_sizes, int n_in,
                              void* d_out, int out_size, void* d_ws, size_t ws_size,
                              hipStream_t stream){
  (void)in_sizes; (void)n_in; (void)out_size; (void)ws_size;
  const void* x    = d_in[0];
  const int* ei    = (const int*)d_in[1];
  const void* eattr= d_in[2];
  // d_in[9] = conv bias: cancels under BN mean-subtraction, skipped
  char* p = (char*)d_ws;
  auto alloc = [&](size_t b)->void*{ void* q = p; p += (b + 255) & ~(size_t)255; return q; };
  float* h      = (float*)alloc((size_t)NN*DIM*4);    // attn output (raw agg); BN fused downstream
  u16*   gl     = (u16*)  alloc((size_t)NN*DIM*2);
  u16*   gr     = (u16*)  alloc((size_t)NN*DIM*2);
  int*   offs   = (int*)  alloc((size_t)(NN+1)*4);
  int*   counts = (int*)  alloc((size_t)NN*4);
  int*   srcs   = (int*)  alloc((size_t)NE*4);
  u16*   eperm  = (u16*)  alloc((size_t)NE*EDIM*2);   // edge_attr in CSR order, bf16
  float* stats  = (float*)alloc(NL*256*4);            // per-layer BN stats, zeroed once
  int*   bsums  = (int*)  alloc(128*4);
  int*   flags  = (int*)  alloc(8);                   // [0]=fflag, [1]=iflag
  u16*   cpar   = (u16*)  alloc((size_t)SEG_TOTAL*2);

  int* fflag = flags;
  int* iflag = flags + 1;

  k_zero32<<<1,256,0,stream>>>(flags, 2);
  k_probe_f<<<1,256,0,stream>>>((const u16*)x, fflag);
  k_probe_i<<<4,256,0,stream>>>(ei, iflag);
  k_cvt_params<<<(SEG_TOTAL+255)/256,256,0,stream>>>(d_in[3], d_in[5], d_in[7], d_in[8],
      d_in[10], d_in[11], d_in[12], d_in[13], d_in[4], d_in[6], cpar, fflag);
  const u16* cWlT= cpar + SEG_WL;  const u16* cWrT= cpar + SEG_WR;
  const u16* cAtt= cpar + SEG_ATT;
  const u16* cGam= cpar + SEG_GAM; const u16* cBet= cpar + SEG_BET;
  const u16* cWfT= cpar + SEG_WF;  const u16* cBf = cpar + SEG_BF;
  const u16* cBl = cpar + SEG_BL;  const u16* cBr = cpar + SEG_BR;
  const u16* cWeT= cpar + SEG_WET;

  k_zero32<<<(NN+255)/256,256,0,stream>>>(counts, NN);
  k_zerof<<<(NL*256+255)/256,256,0,stream>>>(stats, NL*256);
  k_count<<<(NE+255)/256,256,0,stream>>>(ei, iflag, counts);
  const int nbA = (NN+1023)/1024;
  k_scanA<<<nbA,1024,0,stream>>>(counts, offs, bsums);
  k_scanB<<<1,1,0,stream>>>(bsums, offs, nbA);
  k_scanC<<<(NN+255)/256,256,0,stream>>>(offs, bsums);
  k_zero32<<<(NN+255)/256,256,0,stream>>>(counts, NN);
  k_fill<<<(NE+255)/256,256,0,stream>>>(ei, iflag, offs, counts, srcs, eperm, eattr, fflag);

  for (int L=0; L<NL; ++L){
    if (L == 0)
      k_gemm<<<dim3((NN+63)/64,2),256,0,stream>>>(x, 1, nullptr, nullptr, nullptr,
          cWlT + (size_t)L*DIM*DIM, cBl + L*DIM, gl,
          cWrT + (size_t)L*DIM*DIM, cBr + L*DIM, gr, 0, fflag);
    else
      k_gemm<<<dim3((NN+63)/64,2),256,0,stream>>>(h, 0, stats + (L-1)*256, cGam + (L-1)*DIM, cBet + (L-1)*DIM,
          cWlT + (size_t)L*DIM*DIM, cBl + L*DIM, gl,
          cWrT + (size_t)L*DIM*DIM, cBr + L*DIM, gr, 0, fflag);
    // attn writes raw agg into h and accumulates BN stats for this layer
    k_attn<<<2048,256,0,stream>>>(offs, srcs, eperm,
        cWeT + (size_t)L*DIM*EDIM, cAtt + L*DIM, gl, gr, h, stats + L*256);
  }
  // final projection with BN(layer2)+leaky fused on the input
  k_gemm<<<dim3((NN+63)/64,1),256,0,stream>>>(h, 0, stats + 2*256, cGam + 2*DIM, cBet + 2*DIM,
      cWfT, cBf, d_out, cWfT, cBf, d_out, 1, fflag);
}

// Round 6
// 1171.834 us; speedup vs baseline: 1.3402x; 1.0015x over previous
//
#include <hip/hip_runtime.h>

#define NN 100000
#define NE 1600000
#define DIM 128
#define EDIM 16
#define NL 3

typedef unsigned short u16;
typedef unsigned int u32;
typedef __attribute__((ext_vector_type(8))) short bf16x8;
typedef __attribute__((ext_vector_type(4))) float f32x4;

__device__ __forceinline__ float b2f(u16 u){ u32 x = ((u32)u)<<16; float f; __builtin_memcpy(&f,&x,4); return f; }
__device__ __forceinline__ float b2f_lo(u32 u){ u32 x = u<<16; float f; __builtin_memcpy(&f,&x,4); return f; }
__device__ __forceinline__ float b2f_hi(u32 u){ u32 x = u & 0xffff0000u; float f; __builtin_memcpy(&f,&x,4); return f; }
__device__ __forceinline__ u16 f2b(float f){ u32 x; __builtin_memcpy(&x,&f,4); u32 r = (x + 0x7fffu + ((x>>16)&1u))>>16; return (u16)r; }
__device__ __forceinline__ float fexp2(float x){ return __builtin_amdgcn_exp2f(x); }

// DPP rotation-add within 16-lane rows: part += ror<N>(part).
// NOTE: must stay a builtin (NOT inline asm) — the compiler inserts the required
// VALU-write -> DPP-read hazard s_nops; raw asm skips them (round-4 failure).
template<int N>
__device__ __forceinline__ float dpp_ror_add(float v){
  int x; __builtin_memcpy(&x, &v, 4);
  int y = __builtin_amdgcn_update_dpp(0, x, 0x120 | N, 0xF, 0xF, true);
  float r; __builtin_memcpy(&r, &y, 4);
  return v + r;
}

// ---------------- dtype probes ----------------
__global__ void k_probe_f(const u16* __restrict__ x, int* fflag){
  __shared__ int cnt;
  if (threadIdx.x==0) cnt = 0;
  __syncthreads();
  int sane = 0;
  for (int j=threadIdx.x; j<2048; j+=256){
    u16 w = x[j];
    int e = (w>>7)&0xFF;
    if (w==0 || (e>=100 && e<=140)) sane++;
  }
  atomicAdd(&cnt, sane);
  __syncthreads();
  if (threadIdx.x==0) *fflag = (cnt < 1900) ? 1 : 0;   // 1 => float32
}
__global__ void k_probe_i(const int* __restrict__ ei, int* iflag){
  int j = blockIdx.x*256 + threadIdx.x;
  if (j < 1024){ if (ei[2*j+1] != 0) atomicOr(iflag, 1); }  // !=0 => int32
}

// ---------------- utility ----------------
__global__ void k_zero32(int* p, int n){ int i = blockIdx.x*256 + threadIdx.x; if (i<n) p[i]=0; }
__global__ void k_zerof(float* p, int n){ int i = blockIdx.x*256 + threadIdx.x; if (i<n) p[i]=0.f; }

// canonical bf16 params; Wl/Wr/Wf stored TRANSPOSED (dst[c][k] = src[k][c])
// WET = We transposed per layer: WeT[l][c][k] = We[l][k][c]
#define SEG_WL    0
#define SEG_WR    49152
#define SEG_WE    98304
#define SEG_ATT   104448
#define SEG_GAM   104832
#define SEG_BET   105216
#define SEG_WF    105600
#define SEG_BF    121984
#define SEG_BL    122112
#define SEG_BR    122496
#define SEG_WET   122880
#define SEG_TOTAL 129024

__global__ void k_cvt_params(const void* Wl, const void* Wr, const void* We, const void* att,
                             const void* gam, const void* bet, const void* Wf, const void* bf,
                             const void* bl, const void* br,
                             u16* __restrict__ dst, const int* __restrict__ fflag){
  int i = blockIdx.x*256 + threadIdx.x;
  if (i >= SEG_TOTAL) return;
  const void* src; int off;
  if (i < SEG_WR){                       // Wl^T
    int o = i - SEG_WL; int l = o>>14, r = o&16383, c = r>>7, k = r&127;
    src = Wl; off = (l<<14)|(k<<7)|c;
  } else if (i < SEG_WE){                // Wr^T
    int o = i - SEG_WR; int l = o>>14, r = o&16383, c = r>>7, k = r&127;
    src = Wr; off = (l<<14)|(k<<7)|c;
  } else if (i < SEG_ATT){ src = We;  off = i - SEG_WE; }
  else if (i < SEG_GAM)  { src = att; off = i - SEG_ATT; }
  else if (i < SEG_BET)  { src = gam; off = i - SEG_GAM; }
  else if (i < SEG_WF)   { src = bet; off = i - SEG_BET; }
  else if (i < SEG_BF){                  // Wf^T
    int o = i - SEG_WF; int c = o>>7, k = o&127;
    src = Wf; off = (k<<7)|c;
  }
  else if (i < SEG_BL)   { src = bf;  off = i - SEG_BF; }
  else if (i < SEG_BR)   { src = bl;  off = i - SEG_BL; }
  else if (i < SEG_WET)  { src = br;  off = i - SEG_BR; }
  else {                                 // We^T: [l][c][k] <- We[l][k][c]
    int o = i - SEG_WET; int l = o>>11, r = o&2047, c = r>>4, k = r&15;
    src = We; off = (l<<11)|(k<<7)|c;
  }
  dst[i] = (*fflag) ? f2b(((const float*)src)[off]) : ((const u16*)src)[off];
}

// ---------------- CSR build ----------------
__global__ void k_count(const int* __restrict__ ei, const int* __restrict__ iflag, int* __restrict__ counts){
  int e = blockIdx.x*256 + threadIdx.x; if (e >= NE) return;
  int d;
  if (*iflag) d = ei[NE + e];
  else        d = (int)((const long long*)ei)[NE + e];
  atomicAdd(&counts[d], 1);
}
__global__ void k_scanA(const int* __restrict__ counts, int* __restrict__ offs, int* __restrict__ bsums){
  __shared__ int s[1024];
  int t = threadIdx.x; int i = blockIdx.x*1024 + t;
  int v = (i < NN) ? counts[i] : 0;
  s[t] = v; __syncthreads();
  for (int off=1; off<1024; off<<=1){
    int x = (t>=off) ? s[t-off] : 0;
    __syncthreads();
    s[t] += x;
    __syncthreads();
  }
  if (i < NN) offs[i] = s[t] - v;
  if (t == 1023) bsums[blockIdx.x] = s[1023];
}
__global__ void k_scanB(int* bsums, int* offs, int nb){
  if (threadIdx.x==0 && blockIdx.x==0){
    int run = 0;
    for (int j=0;j<nb;j++){ int tmp=bsums[j]; bsums[j]=run; run+=tmp; }
    offs[NN] = run;
  }
}
__global__ void k_scanC(int* __restrict__ offs, const int* __restrict__ bsums){
  int i = blockIdx.x*256 + threadIdx.x;
  if (i < NN) offs[i] += bsums[i>>10];
}

// fill CSR: srcs + edge_attr permuted into CSR order as bf16 (eperm)
__global__ void k_fill(const int* __restrict__ ei, const int* __restrict__ iflag,
                       const int* __restrict__ offs, int* __restrict__ counts,
                       int* __restrict__ srcs, u16* __restrict__ eperm,
                       const void* __restrict__ eattr, const int* __restrict__ fflag){
  int e = blockIdx.x*256 + threadIdx.x; if (e >= NE) return;
  int s, d;
  if (*iflag){ s = ei[e]; d = ei[NE + e]; }
  else { const long long* e64 = (const long long*)ei; s = (int)e64[e]; d = (int)e64[NE + e]; }
  int pos = offs[d] + atomicAdd(&counts[d], 1);
  srcs[pos] = s;
  uint4 lo, hi;
  if (*fflag){
    const float4* s4 = (const float4*)((const float*)eattr + (size_t)e*EDIM);
    float4 a = s4[0], b = s4[1], c = s4[2], dd = s4[3];
    lo.x = (u32)f2b(a.x) | ((u32)f2b(a.y)<<16); lo.y = (u32)f2b(a.z) | ((u32)f2b(a.w)<<16);
    lo.z = (u32)f2b(b.x) | ((u32)f2b(b.y)<<16); lo.w = (u32)f2b(b.z) | ((u32)f2b(b.w)<<16);
    hi.x = (u32)f2b(c.x) | ((u32)f2b(c.y)<<16); hi.y = (u32)f2b(c.z) | ((u32)f2b(c.w)<<16);
    hi.z = (u32)f2b(dd.x)| ((u32)f2b(dd.y)<<16);hi.w = (u32)f2b(dd.z)| ((u32)f2b(dd.w)<<16);
  } else {
    const uint4* s4 = (const uint4*)((const u16*)eattr + (size_t)e*EDIM);
    lo = s4[0]; hi = s4[1];
  }
  uint4* dst = (uint4*)(eperm + (size_t)pos*EDIM);
  dst[0] = lo; dst[1] = hi;
}

// ---------------- MFMA node GEMM with optional fused BN+leaky on the input ----------------
// out[n][c] = sum_k f(in[n][k])*W[k][c] + b[c], f = BN-affine + leaky(0.02) when st!=null.
// in_raw: read input directly (f32 or bf16 per fflag). WT = transposed weight [c][k] bf16.
#define LSTR 136   // padded LDS row stride (bf16 elems): +16B breaks bank conflicts
__global__ __launch_bounds__(256) void k_gemm(const void* __restrict__ in, int in_raw,
    const float* __restrict__ st, const u16* __restrict__ gm, const u16* __restrict__ bt,
    const u16* __restrict__ WT0, const u16* __restrict__ b0, void* __restrict__ out0,
    const u16* __restrict__ WT1, const u16* __restrict__ b1, void* __restrict__ out1,
    int store_f32, const int* __restrict__ fflag)
{
  __shared__ __align__(16) u16 Xs[64*LSTR];
  __shared__ __align__(16) u16 Ws[128*LSTR];
  __shared__ __align__(16) float sA[DIM], sB[DIM];
  const u16* WT = blockIdx.y ? WT1 : WT0;
  const u16* bi = blockIdx.y ? b1 : b0;
  void* out     = blockIdx.y ? out1 : out0;
  int t = threadIdx.x;
  int n0 = blockIdx.x*64;
  // stage W^T (128x128 bf16 = 2048 uint4), coalesced
  const uint4* w4 = (const uint4*)WT;
  for (int p = t; p < 2048; p += 256){
    int c = p >> 4, k16 = p & 15;
    *(uint4*)&Ws[c*LSTR + k16*8] = w4[p];
  }
  // BN affine coefficients: y = v*A[c] + B[c]
  if (st && t < DIM){
    const float invN = 1.f/(float)NN;
    float mu = st[t]*invN;
    float va = st[DIM+t]*invN - mu*mu;
    float rs = rsqrtf(fmaxf(va, 0.f) + 1e-5f);
    float A = rs*b2f(gm[t]);
    sA[t] = A;
    sB[t] = b2f(bt[t]) - mu*A;
  }
  __syncthreads();
  // stage X (64x128 -> bf16), optional BN+leaky
  for (int p = t; p < 2048; p += 256){
    int r = p >> 5, c4 = p & 31;
    int n = n0 + r;
    uint2 pk = make_uint2(0,0);
    if (n < NN){
      if (in_raw && !(*fflag)){
        pk = *(const uint2*)((const u16*)in + (size_t)n*DIM + c4*4);
      } else {
        float4 v = *(const float4*)((const float*)in + (size_t)n*DIM + c4*4);
        if (st){
          int c = c4*4;
          float4 Af = *(const float4*)&sA[c];
          float4 Bf = *(const float4*)&sB[c];
          v.x = v.x*Af.x + Bf.x; v.x = fmaxf(v.x, 0.02f*v.x);
          v.y = v.y*Af.y + Bf.y; v.y = fmaxf(v.y, 0.02f*v.y);
          v.z = v.z*Af.z + Bf.z; v.z = fmaxf(v.z, 0.02f*v.z);
          v.w = v.w*Af.w + Bf.w; v.w = fmaxf(v.w, 0.02f*v.w);
        }
        pk.x = (u32)f2b(v.x) | ((u32)f2b(v.y)<<16);
        pk.y = (u32)f2b(v.z) | ((u32)f2b(v.w)<<16);
      }
    }
    *(uint2*)&Xs[r*LSTR + c4*4] = pk;
  }
  __syncthreads();
  int lane = t & 63, wv = t >> 6;
  int m = lane & 15, q = lane >> 4;
  f32x4 acc[8];
  #pragma unroll
  for (int i=0;i<8;i++) acc[i] = (f32x4){0.f,0.f,0.f,0.f};
  #pragma unroll
  for (int ks=0; ks<4; ks++){
    bf16x8 af = *(const bf16x8*)&Xs[(wv*16 + m)*LSTR + ks*32 + q*8];
    #pragma unroll
    for (int nt=0; nt<8; nt++){
      bf16x8 bfr = *(const bf16x8*)&Ws[(nt*16 + m)*LSTR + ks*32 + q*8];
      acc[nt] = __builtin_amdgcn_mfma_f32_16x16x32_bf16(af, bfr, acc[nt], 0, 0, 0);
    }
  }
  bool f32out = store_f32 && (*fflag);
  #pragma unroll
  for (int nt=0; nt<8; nt++){
    int col = nt*16 + m;
    float bvv = b2f(bi[col]);
    #pragma unroll
    for (int r=0;r<4;r++){
      int row = n0 + wv*16 + q*4 + r;
      if (row < NN){
        float val = acc[nt][r] + bvv;
        if (f32out) ((float*)out)[(size_t)row*DIM + col] = val;
        else        ((u16*)out)[(size_t)row*DIM + col] = f2b(val);
      }
    }
  }
}

// ---------------- attention (+ fused BN-stats) ----------------
// One wave per node (grid-stride). Per 16-edge CSR tile, el = eperm_tile @ We on the
// matrix pipe: mfma(af, bwe[tc]) -> D[edge][ch], scattered per-reg into el[edge][ELP]
// (bank = m + 16*(q&1) + ... -> exact 2-way aliasing = free; the round-5 b128 variant
// was an 8-way conflict and SLOWER — reverted). Online softmax with builtin-DPP
// rotation reduce; BN stats accumulated in registers, block-merged in the epilogue.
#define ELP 132  // el row stride (f32): 528B/row -> 2-way bank aliasing on write+read (free)
__global__ __launch_bounds__(256,4) void k_attn(const int* __restrict__ offs, const int* __restrict__ srcs,
    const u16* __restrict__ eperm, const u16* __restrict__ WeT, const u16* __restrict__ att,
    const u16* __restrict__ gl, const u16* __restrict__ gr, float* __restrict__ agg,
    float* __restrict__ stats)
{
  __shared__ __align__(16) float sEl[4][16*ELP];   // per-wave el tiles, 33.8 KB
  int t = threadIdx.x;
  int lane = t & 63, wv = t >> 6;
  int m = lane & 15, q = lane >> 4;
  // loop-invariant fragments of We^T: bwe[tc] holds WeT[tc*16+m][q*8..q*8+7] (zero for k>=16)
  bf16x8 bwe[8];
  #pragma unroll
  for (int tc = 0; tc < 8; ++tc){
    if (q < 2) bwe[tc] = *(const bf16x8*)&WeT[(tc*16 + m)*16 + q*8];
    else       bwe[tc] = (bf16x8){0,0,0,0,0,0,0,0};
  }
  // fold log2(e) into att so exponentials are native exp2 (alpha mathematically identical)
  const float LOG2E = 1.442695041f;
  float att0 = b2f(att[2*lane])*LOG2E, att1 = b2f(att[2*lane+1])*LOG2E;
  float* el = &sEl[wv][0];
  const u32* glv = (const u32*)gl + lane;   // lane folded into base
  float s0=0.f, s1=0.f, sq0=0.f, sq1=0.f;   // BN-stats accumulators (lane owns chs 2l,2l+1)

  for (int node = blockIdx.x*4 + wv; node < NN; node += gridDim.x*4){
    u32 g = ((const u32*)gr)[(size_t)node*64 + lane];
    float gr0 = b2f_lo(g), gr1 = b2f_hi(g);
    float ms[4], ds[4], o0[4], o1[4];
    #pragma unroll
    for (int i=0;i<4;i++){ ms[i] = -INFINITY; ds[i]=0.f; o0[i]=0.f; o1[i]=0.f; }
    int beg = offs[node], end = offs[node+1];
    // prefetch first tile's A-fragment
    bf16x8 af = (bf16x8){0,0,0,0,0,0,0,0};
    if (q < 2 && beg < end){
      int eidx = beg + m; eidx = eidx < NE ? eidx : NE-1;
      af = *(const bf16x8*)&eperm[(size_t)eidx*EDIM + q*8];
    }
    for (int tb = beg; tb < end; tb += 16){
      // ---- el tile on matrix pipe; per-reg scatter (2-way banks = free) ----
      #pragma unroll
      for (int tc = 0; tc < 8; ++tc){
        f32x4 d = __builtin_amdgcn_mfma_f32_16x16x32_bf16(af, bwe[tc], (f32x4){0.f,0.f,0.f,0.f}, 0, 0, 0);
        #pragma unroll
        for (int r = 0; r < 4; ++r)
          el[(q*4 + r)*ELP + tc*16 + m] = d[r];     // edge=q*4+r, ch=tc*16+m
      }
      // prefetch NEXT tile's A-fragment (hides eperm latency under consume)
      if (q < 2){
        int eidx = tb + 16 + m; eidx = eidx < NE ? eidx : NE-1;
        af = *(const bf16x8*)&eperm[(size_t)eidx*EDIM + q*8];
      }
      // same-wave LDS write->read: in-order DS pipe + compiler lgkmcnt, no barrier needed
      int tend = end < tb + 16 ? end : tb + 16;
      int e = tb;
      for (; e + 4 <= tend; e += 4){
        int sidx[4];
        #pragma unroll
        for (int i=0;i<4;i++) sidx[i] = srcs[e+i];
        u32 gx[4];
        #pragma unroll
        for (int i=0;i<4;i++) gx[i] = glv[(u32)sidx[i]<<6];
        float2 ev[4];
        #pragma unroll
        for (int i=0;i<4;i++) ev[i] = *(const float2*)&el[(e - tb + i)*ELP + 2*lane];
        #pragma unroll
        for (int i=0;i<4;i++){
          float xj0 = b2f_lo(gx[i]), xj1 = b2f_hi(gx[i]);
          float e0 = xj0 + gr0 + ev[i].x;
          float e1 = xj1 + gr1 + ev[i].y;
          e0 = fmaxf(e0, 0.2f*e0);
          e1 = fmaxf(e1, 0.2f*e1);
          float part = e0*att0 + e1*att1;          // log2-domain logit
          part = dpp_ror_add<1>(part);
          part = dpp_ror_add<2>(part);
          part = dpp_ror_add<4>(part);
          part = dpp_ror_add<8>(part);
          float nm = fmaxf(ms[i], part);
          float sc = fexp2(ms[i] - nm);            // -inf -> 0 on first edge
          float pp = fexp2(part - nm);
          ds[i] = ds[i]*sc + pp;
          o0[i] = o0[i]*sc + pp*xj0;
          o1[i] = o1[i]*sc + pp*xj1;
          ms[i] = nm;
        }
      }
      for (; e < tend; ++e){
        int s = srcs[e];
        u32 gx = glv[(u32)s<<6];
        float2 ev = *(const float2*)&el[(e - tb)*ELP + 2*lane];
        float xj0 = b2f_lo(gx), xj1 = b2f_hi(gx);
        float e0 = xj0 + gr0 + ev.x;
        float e1 = xj1 + gr1 + ev.y;
        e0 = fmaxf(e0, 0.2f*e0);
        e1 = fmaxf(e1, 0.2f*e1);
        float part = e0*att0 + e1*att1;
        part = dpp_ror_add<1>(part);
        part = dpp_ror_add<2>(part);
        part = dpp_ror_add<4>(part);
        part = dpp_ror_add<8>(part);
        float nm = fmaxf(ms[0], part);
        float sc = fexp2(ms[0] - nm);
        float pp = fexp2(part - nm);
        ds[0] = ds[0]*sc + pp;
        o0[0] = o0[0]*sc + pp*xj0;
        o1[0] = o1[0]*sc + pp*xj1;
        ms[0] = nm;
      }
    }
    // merge states (guard -inf: empty state contributes 0)
    float M = fmaxf(fmaxf(ms[0],ms[1]), fmaxf(ms[2],ms[3]));
    float D = 0.f, P0 = 0.f, P1 = 0.f;
    #pragma unroll
    for (int i=0;i<4;i++){
      if (ms[i] != -INFINITY){
        float sc = fexp2(ms[i] - M);
        D += sc*ds[i]; P0 += sc*o0[i]; P1 += sc*o1[i];
      }
    }
    float inv = 1.f/(D + 1e-16f);
    float v0 = P0*inv, v1 = P1*inv;
    s0 += v0; s1 += v1; sq0 += v0*v0; sq1 += v1*v1;
    ((float2*)agg)[(size_t)node*64 + lane] = make_float2(v0, v1);
  }
  // ---- block-reduce BN stats (sEl is dead; each wave writes only its own slice) ----
  {
    float* sp = &sEl[wv][0];
    sp[lane*4+0]=s0; sp[lane*4+1]=s1; sp[lane*4+2]=sq0; sp[lane*4+3]=sq1;
    __syncthreads();
    if (wv == 0){
      float a0=0,a1=0,b0=0,b1=0;
      #pragma unroll
      for (int w=0; w<4; ++w){
        a0 += sEl[w][lane*4+0]; a1 += sEl[w][lane*4+1];
        b0 += sEl[w][lane*4+2]; b1 += sEl[w][lane*4+3];
      }
      int c0 = 2*lane;
      atomicAdd(&stats[c0],     a0); atomicAdd(&stats[c0+1],     a1);
      atomicAdd(&stats[DIM+c0], b0); atomicAdd(&stats[DIM+c0+1], b1);
    }
  }
}

// ---------------- launch ----------------
extern "C" void kernel_launch(void* const* d_in, const int* in_sizes, int n_in,
                              void* d_out, int out_size, void* d_ws, size_t ws_size,
                              hipStream_t stream){
  (void)in_sizes; (void)n_in; (void)out_size; (void)ws_size;
  const void* x    = d_in[0];
  const int* ei    = (const int*)d_in[1];
  const void* eattr= d_in[2];
  // d_in[9] = conv bias: cancels under BN mean-subtraction, skipped
  char* p = (char*)d_ws;
  auto alloc = [&](size_t b)->void*{ void* q = p; p += (b + 255) & ~(size_t)255; return q; };
  float* h      = (float*)alloc((size_t)NN*DIM*4);    // attn output (raw agg); BN fused downstream
  u16*   gl     = (u16*)  alloc((size_t)NN*DIM*2);
  u16*   gr     = (u16*)  alloc((size_t)NN*DIM*2);
  int*   offs   = (int*)  alloc((size_t)(NN+1)*4);
  int*   counts = (int*)  alloc((size_t)NN*4);
  int*   srcs   = (int*)  alloc((size_t)NE*4);
  u16*   eperm  = (u16*)  alloc((size_t)NE*EDIM*2);   // edge_attr in CSR order, bf16
  float* stats  = (float*)alloc(NL*256*4);            // per-layer BN stats, zeroed once
  int*   bsums  = (int*)  alloc(128*4);
  int*   flags  = (int*)  alloc(8);                   // [0]=fflag, [1]=iflag
  u16*   cpar   = (u16*)  alloc((size_t)SEG_TOTAL*2);

  int* fflag = flags;
  int* iflag = flags + 1;

  k_zero32<<<1,256,0,stream>>>(flags, 2);
  k_probe_f<<<1,256,0,stream>>>((const u16*)x, fflag);
  k_probe_i<<<4,256,0,stream>>>(ei, iflag);
  k_cvt_params<<<(SEG_TOTAL+255)/256,256,0,stream>>>(d_in[3], d_in[5], d_in[7], d_in[8],
      d_in[10], d_in[11], d_in[12], d_in[13], d_in[4], d_in[6], cpar, fflag);
  const u16* cWlT= cpar + SEG_WL;  const u16* cWrT= cpar + SEG_WR;
  const u16* cAtt= cpar + SEG_ATT;
  const u16* cGam= cpar + SEG_GAM; const u16* cBet= cpar + SEG_BET;
  const u16* cWfT= cpar + SEG_WF;  const u16* cBf = cpar + SEG_BF;
  const u16* cBl = cpar + SEG_BL;  const u16* cBr = cpar + SEG_BR;
  const u16* cWeT= cpar + SEG_WET;

  k_zero32<<<(NN+255)/256,256,0,stream>>>(counts, NN);
  k_zerof<<<(NL*256+255)/256,256,0,stream>>>(stats, NL*256);
  k_count<<<(NE+255)/256,256,0,stream>>>(ei, iflag, counts);
  const int nbA = (NN+1023)/1024;
  k_scanA<<<nbA,1024,0,stream>>>(counts, offs, bsums);
  k_scanB<<<1,1,0,stream>>>(bsums, offs, nbA);
  k_scanC<<<(NN+255)/256,256,0,stream>>>(offs, bsums);
  k_zero32<<<(NN+255)/256,256,0,stream>>>(counts, NN);
  k_fill<<<(NE+255)/256,256,0,stream>>>(ei, iflag, offs, counts, srcs, eperm, eattr, fflag);

  for (int L=0; L<NL; ++L){
    if (L == 0)
      k_gemm<<<dim3((NN+63)/64,2),256,0,stream>>>(x, 1, nullptr, nullptr, nullptr,
          cWlT + (size_t)L*DIM*DIM, cBl + L*DIM, gl,
          cWrT + (size_t)L*DIM*DIM, cBr + L*DIM, gr, 0, fflag);
    else
      k_gemm<<<dim3((NN+63)/64,2),256,0,stream>>>(h, 0, stats + (L-1)*256, cGam + (L-1)*DIM, cBet + (L-1)*DIM,
          cWlT + (size_t)L*DIM*DIM, cBl + L*DIM, gl,
          cWrT + (size_t)L*DIM*DIM, cBr + L*DIM, gr, 0, fflag);
    // attn writes raw agg into h and accumulates BN stats for this layer
    k_attn<<<2048,256,0,stream>>>(offs, srcs, eperm,
        cWeT + (size_t)L*DIM*EDIM, cAtt + L*DIM, gl, gr, h, stats + L*256);
  }
  // final projection with BN(layer2)+leaky fused on the input
  k_gemm<<<dim3((NN+63)/64,1),256,0,stream>>>(h, 0, stats + 2*256, cGam + 2*DIM, cBet + 2*DIM,
      cWfT, cBf, d_out, cWfT, cBf, d_out, 1, fflag);
}

// Round 7
// 1052.496 us; speedup vs baseline: 1.4922x; 1.1134x over previous
//
#include <hip/hip_runtime.h>

#define NN 100000
#define NE 1600000
#define DIM 128
#define EDIM 16
#define NL 3
#define NREP 8   // BN-stats atomic replicas (contention spreader)

typedef unsigned short u16;
typedef unsigned int u32;
typedef __attribute__((ext_vector_type(8))) short bf16x8;
typedef __attribute__((ext_vector_type(4))) float f32x4;

__device__ __forceinline__ float b2f(u16 u){ u32 x = ((u32)u)<<16; float f; __builtin_memcpy(&f,&x,4); return f; }
__device__ __forceinline__ float b2f_lo(u32 u){ u32 x = u<<16; float f; __builtin_memcpy(&f,&x,4); return f; }
__device__ __forceinline__ float b2f_hi(u32 u){ u32 x = u & 0xffff0000u; float f; __builtin_memcpy(&f,&x,4); return f; }
__device__ __forceinline__ u16 f2b(float f){ u32 x; __builtin_memcpy(&x,&f,4); u32 r = (x + 0x7fffu + ((x>>16)&1u))>>16; return (u16)r; }
__device__ __forceinline__ float fexp2(float x){ return __builtin_amdgcn_exp2f(x); }

// DPP rotation-add within 16-lane rows: part += ror<N>(part).
// NOTE: must stay a builtin (NOT inline asm) — the compiler inserts the required
// VALU-write -> DPP-read hazard s_nops; raw asm skips them (round-4 failure).
template<int N>
__device__ __forceinline__ float dpp_ror_add(float v){
  int x; __builtin_memcpy(&x, &v, 4);
  int y = __builtin_amdgcn_update_dpp(0, x, 0x120 | N, 0xF, 0xF, true);
  float r; __builtin_memcpy(&r, &y, 4);
  return v + r;
}

// ---------------- dtype probes ----------------
__global__ void k_probe_f(const u16* __restrict__ x, int* fflag){
  __shared__ int cnt;
  if (threadIdx.x==0) cnt = 0;
  __syncthreads();
  int sane = 0;
  for (int j=threadIdx.x; j<2048; j+=256){
    u16 w = x[j];
    int e = (w>>7)&0xFF;
    if (w==0 || (e>=100 && e<=140)) sane++;
  }
  atomicAdd(&cnt, sane);
  __syncthreads();
  if (threadIdx.x==0) *fflag = (cnt < 1900) ? 1 : 0;   // 1 => float32
}
__global__ void k_probe_i(const int* __restrict__ ei, int* iflag){
  int j = blockIdx.x*256 + threadIdx.x;
  if (j < 1024){ if (ei[2*j+1] != 0) atomicOr(iflag, 1); }  // !=0 => int32
}

// ---------------- utility ----------------
__global__ void k_zero32(int* p, int n){ int i = blockIdx.x*256 + threadIdx.x; if (i<n) p[i]=0; }
__global__ void k_zerof(float* p, int n){ int i = blockIdx.x*256 + threadIdx.x; if (i<n) p[i]=0.f; }

// canonical bf16 params; Wl/Wr/Wf stored TRANSPOSED (dst[c][k] = src[k][c])
// WET = We transposed per layer: WeT[l][c][k] = We[l][k][c]
#define SEG_WL    0
#define SEG_WR    49152
#define SEG_WE    98304
#define SEG_ATT   104448
#define SEG_GAM   104832
#define SEG_BET   105216
#define SEG_WF    105600
#define SEG_BF    121984
#define SEG_BL    122112
#define SEG_BR    122496
#define SEG_WET   122880
#define SEG_TOTAL 129024

__global__ void k_cvt_params(const void* Wl, const void* Wr, const void* We, const void* att,
                             const void* gam, const void* bet, const void* Wf, const void* bf,
                             const void* bl, const void* br,
                             u16* __restrict__ dst, const int* __restrict__ fflag){
  int i = blockIdx.x*256 + threadIdx.x;
  if (i >= SEG_TOTAL) return;
  const void* src; int off;
  if (i < SEG_WR){                       // Wl^T
    int o = i - SEG_WL; int l = o>>14, r = o&16383, c = r>>7, k = r&127;
    src = Wl; off = (l<<14)|(k<<7)|c;
  } else if (i < SEG_WE){                // Wr^T
    int o = i - SEG_WR; int l = o>>14, r = o&16383, c = r>>7, k = r&127;
    src = Wr; off = (l<<14)|(k<<7)|c;
  } else if (i < SEG_ATT){ src = We;  off = i - SEG_WE; }
  else if (i < SEG_GAM)  { src = att; off = i - SEG_ATT; }
  else if (i < SEG_BET)  { src = gam; off = i - SEG_GAM; }
  else if (i < SEG_WF)   { src = bet; off = i - SEG_BET; }
  else if (i < SEG_BF){                  // Wf^T
    int o = i - SEG_WF; int c = o>>7, k = o&127;
    src = Wf; off = (k<<7)|c;
  }
  else if (i < SEG_BL)   { src = bf;  off = i - SEG_BF; }
  else if (i < SEG_BR)   { src = bl;  off = i - SEG_BL; }
  else if (i < SEG_WET)  { src = br;  off = i - SEG_BR; }
  else {                                 // We^T: [l][c][k] <- We[l][k][c]
    int o = i - SEG_WET; int l = o>>11, r = o&2047, c = r>>4, k = r&15;
    src = We; off = (l<<11)|(k<<7)|c;
  }
  dst[i] = (*fflag) ? f2b(((const float*)src)[off]) : ((const u16*)src)[off];
}

// ---------------- CSR build ----------------
__global__ void k_count(const int* __restrict__ ei, const int* __restrict__ iflag, int* __restrict__ counts){
  int e = blockIdx.x*256 + threadIdx.x; if (e >= NE) return;
  int d;
  if (*iflag) d = ei[NE + e];
  else        d = (int)((const long long*)ei)[NE + e];
  atomicAdd(&counts[d], 1);
}
__global__ void k_scanA(const int* __restrict__ counts, int* __restrict__ offs, int* __restrict__ bsums){
  __shared__ int s[1024];
  int t = threadIdx.x; int i = blockIdx.x*1024 + t;
  int v = (i < NN) ? counts[i] : 0;
  s[t] = v; __syncthreads();
  for (int off=1; off<1024; off<<=1){
    int x = (t>=off) ? s[t-off] : 0;
    __syncthreads();
    s[t] += x;
    __syncthreads();
  }
  if (i < NN) offs[i] = s[t] - v;
  if (t == 1023) bsums[blockIdx.x] = s[1023];
}
__global__ void k_scanB(int* bsums, int* offs, int nb){
  if (threadIdx.x==0 && blockIdx.x==0){
    int run = 0;
    for (int j=0;j<nb;j++){ int tmp=bsums[j]; bsums[j]=run; run+=tmp; }
    offs[NN] = run;
  }
}
__global__ void k_scanC(int* __restrict__ offs, const int* __restrict__ bsums){
  int i = blockIdx.x*256 + threadIdx.x;
  if (i < NN) offs[i] += bsums[i>>10];
}

// fill CSR: srcs + edge_attr permuted into CSR order as bf16 (eperm)
__global__ void k_fill(const int* __restrict__ ei, const int* __restrict__ iflag,
                       const int* __restrict__ offs, int* __restrict__ counts,
                       int* __restrict__ srcs, u16* __restrict__ eperm,
                       const void* __restrict__ eattr, const int* __restrict__ fflag){
  int e = blockIdx.x*256 + threadIdx.x; if (e >= NE) return;
  int s, d;
  if (*iflag){ s = ei[e]; d = ei[NE + e]; }
  else { const long long* e64 = (const long long*)ei; s = (int)e64[e]; d = (int)e64[NE + e]; }
  int pos = offs[d] + atomicAdd(&counts[d], 1);
  srcs[pos] = s;
  uint4 lo, hi;
  if (*fflag){
    const float4* s4 = (const float4*)((const float*)eattr + (size_t)e*EDIM);
    float4 a = s4[0], b = s4[1], c = s4[2], dd = s4[3];
    lo.x = (u32)f2b(a.x) | ((u32)f2b(a.y)<<16); lo.y = (u32)f2b(a.z) | ((u32)f2b(a.w)<<16);
    lo.z = (u32)f2b(b.x) | ((u32)f2b(b.y)<<16); lo.w = (u32)f2b(b.z) | ((u32)f2b(b.w)<<16);
    hi.x = (u32)f2b(c.x) | ((u32)f2b(c.y)<<16); hi.y = (u32)f2b(c.z) | ((u32)f2b(c.w)<<16);
    hi.z = (u32)f2b(dd.x)| ((u32)f2b(dd.y)<<16);hi.w = (u32)f2b(dd.z)| ((u32)f2b(dd.w)<<16);
  } else {
    const uint4* s4 = (const uint4*)((const u16*)eattr + (size_t)e*EDIM);
    lo = s4[0]; hi = s4[1];
  }
  uint4* dst = (uint4*)(eperm + (size_t)pos*EDIM);
  dst[0] = lo; dst[1] = hi;
}

// ---------------- MFMA node GEMM with optional fused BN+leaky on the input ----------------
// out[n][c] = sum_k f(in[n][k])*W[k][c] + b[c], f = BN-affine + leaky(0.02) when st!=null.
// st points at NREP stats replicas of [256] (sums in [0,128), sq-sums in [128,256)).
#define LSTR 136   // padded LDS row stride (bf16 elems): +16B breaks bank conflicts
__global__ __launch_bounds__(256) void k_gemm(const void* __restrict__ in, int in_raw,
    const float* __restrict__ st, const u16* __restrict__ gm, const u16* __restrict__ bt,
    const u16* __restrict__ WT0, const u16* __restrict__ b0, void* __restrict__ out0,
    const u16* __restrict__ WT1, const u16* __restrict__ b1, void* __restrict__ out1,
    int store_f32, const int* __restrict__ fflag)
{
  __shared__ __align__(16) u16 Xs[64*LSTR];
  __shared__ __align__(16) u16 Ws[128*LSTR];
  __shared__ __align__(16) float sA[DIM], sB[DIM];
  const u16* WT = blockIdx.y ? WT1 : WT0;
  const u16* bi = blockIdx.y ? b1 : b0;
  void* out     = blockIdx.y ? out1 : out0;
  int t = threadIdx.x;
  int n0 = blockIdx.x*64;
  // stage W^T (128x128 bf16 = 2048 uint4), coalesced
  const uint4* w4 = (const uint4*)WT;
  for (int p = t; p < 2048; p += 256){
    int c = p >> 4, k16 = p & 15;
    *(uint4*)&Ws[c*LSTR + k16*8] = w4[p];
  }
  // BN affine coefficients: y = v*A[c] + B[c] (sum the NREP replicas first)
  if (st && t < DIM){
    float sum = 0.f, sqs = 0.f;
    #pragma unroll
    for (int r = 0; r < NREP; ++r){
      sum += st[r*256 + t];
      sqs += st[r*256 + DIM + t];
    }
    const float invN = 1.f/(float)NN;
    float mu = sum*invN;
    float va = sqs*invN - mu*mu;
    float rs = rsqrtf(fmaxf(va, 0.f) + 1e-5f);
    float A = rs*b2f(gm[t]);
    sA[t] = A;
    sB[t] = b2f(bt[t]) - mu*A;
  }
  __syncthreads();
  // stage X (64x128 -> bf16), optional BN+leaky
  for (int p = t; p < 2048; p += 256){
    int r = p >> 5, c4 = p & 31;
    int n = n0 + r;
    uint2 pk = make_uint2(0,0);
    if (n < NN){
      if (in_raw && !(*fflag)){
        pk = *(const uint2*)((const u16*)in + (size_t)n*DIM + c4*4);
      } else {
        float4 v = *(const float4*)((const float*)in + (size_t)n*DIM + c4*4);
        if (st){
          int c = c4*4;
          float4 Af = *(const float4*)&sA[c];
          float4 Bf = *(const float4*)&sB[c];
          v.x = v.x*Af.x + Bf.x; v.x = fmaxf(v.x, 0.02f*v.x);
          v.y = v.y*Af.y + Bf.y; v.y = fmaxf(v.y, 0.02f*v.y);
          v.z = v.z*Af.z + Bf.z; v.z = fmaxf(v.z, 0.02f*v.z);
          v.w = v.w*Af.w + Bf.w; v.w = fmaxf(v.w, 0.02f*v.w);
        }
        pk.x = (u32)f2b(v.x) | ((u32)f2b(v.y)<<16);
        pk.y = (u32)f2b(v.z) | ((u32)f2b(v.w)<<16);
      }
    }
    *(uint2*)&Xs[r*LSTR + c4*4] = pk;
  }
  __syncthreads();
  int lane = t & 63, wv = t >> 6;
  int m = lane & 15, q = lane >> 4;
  f32x4 acc[8];
  #pragma unroll
  for (int i=0;i<8;i++) acc[i] = (f32x4){0.f,0.f,0.f,0.f};
  #pragma unroll
  for (int ks=0; ks<4; ks++){
    bf16x8 af = *(const bf16x8*)&Xs[(wv*16 + m)*LSTR + ks*32 + q*8];
    #pragma unroll
    for (int nt=0; nt<8; nt++){
      bf16x8 bfr = *(const bf16x8*)&Ws[(nt*16 + m)*LSTR + ks*32 + q*8];
      acc[nt] = __builtin_amdgcn_mfma_f32_16x16x32_bf16(af, bfr, acc[nt], 0, 0, 0);
    }
  }
  bool f32out = store_f32 && (*fflag);
  #pragma unroll
  for (int nt=0; nt<8; nt++){
    int col = nt*16 + m;
    float bvv = b2f(bi[col]);
    #pragma unroll
    for (int r=0;r<4;r++){
      int row = n0 + wv*16 + q*4 + r;
      if (row < NN){
        float val = acc[nt][r] + bvv;
        if (f32out) ((float*)out)[(size_t)row*DIM + col] = val;
        else        ((u16*)out)[(size_t)row*DIM + col] = f2b(val);
      }
    }
  }
}

// ---------------- attention (+ fused BN-stats, replica-scattered atomics) ----------------
// One wave per node (grid-stride). Per 16-edge CSR tile, el = eperm_tile @ We on the
// matrix pipe: mfma(af, bwe[tc]) -> D[edge][ch], scattered per-reg into el[edge][ELP]
// (2-way banks = free). Online softmax with builtin-DPP rotation reduce; BN stats
// accumulated in registers, block-merged, then atomically added into the block's
// replica stats[blockIdx&7][*] (2048-way same-address contention was round-5/6's
// ~35us serialized tail — replicas cut it 8x).
#define ELP 132  // el row stride (f32): 528B/row -> 2-way bank aliasing on write+read (free)
__global__ __launch_bounds__(256,4) void k_attn(const int* __restrict__ offs, const int* __restrict__ srcs,
    const u16* __restrict__ eperm, const u16* __restrict__ WeT, const u16* __restrict__ att,
    const u16* __restrict__ gl, const u16* __restrict__ gr, float* __restrict__ agg,
    float* __restrict__ stats)
{
  __shared__ __align__(16) float sEl[4][16*ELP];   // per-wave el tiles, 33.8 KB
  int t = threadIdx.x;
  int lane = t & 63, wv = t >> 6;
  int m = lane & 15, q = lane >> 4;
  // loop-invariant fragments of We^T: bwe[tc] holds WeT[tc*16+m][q*8..q*8+7] (zero for k>=16)
  bf16x8 bwe[8];
  #pragma unroll
  for (int tc = 0; tc < 8; ++tc){
    if (q < 2) bwe[tc] = *(const bf16x8*)&WeT[(tc*16 + m)*16 + q*8];
    else       bwe[tc] = (bf16x8){0,0,0,0,0,0,0,0};
  }
  // fold log2(e) into att so exponentials are native exp2 (alpha mathematically identical)
  const float LOG2E = 1.442695041f;
  float att0 = b2f(att[2*lane])*LOG2E, att1 = b2f(att[2*lane+1])*LOG2E;
  float* el = &sEl[wv][0];
  const u32* glv = (const u32*)gl + lane;   // lane folded into base
  float s0=0.f, s1=0.f, sq0=0.f, sq1=0.f;   // BN-stats accumulators (lane owns chs 2l,2l+1)

  for (int node = blockIdx.x*4 + wv; node < NN; node += gridDim.x*4){
    u32 g = ((const u32*)gr)[(size_t)node*64 + lane];
    float gr0 = b2f_lo(g), gr1 = b2f_hi(g);
    float ms[4], ds[4], o0[4], o1[4];
    #pragma unroll
    for (int i=0;i<4;i++){ ms[i] = -INFINITY; ds[i]=0.f; o0[i]=0.f; o1[i]=0.f; }
    int beg = offs[node], end = offs[node+1];
    // prefetch first tile's A-fragment
    bf16x8 af = (bf16x8){0,0,0,0,0,0,0,0};
    if (q < 2 && beg < end){
      int eidx = beg + m; eidx = eidx < NE ? eidx : NE-1;
      af = *(const bf16x8*)&eperm[(size_t)eidx*EDIM + q*8];
    }
    for (int tb = beg; tb < end; tb += 16){
      // ---- el tile on matrix pipe; per-reg scatter (2-way banks = free) ----
      #pragma unroll
      for (int tc = 0; tc < 8; ++tc){
        f32x4 d = __builtin_amdgcn_mfma_f32_16x16x32_bf16(af, bwe[tc], (f32x4){0.f,0.f,0.f,0.f}, 0, 0, 0);
        #pragma unroll
        for (int r = 0; r < 4; ++r)
          el[(q*4 + r)*ELP + tc*16 + m] = d[r];     // edge=q*4+r, ch=tc*16+m
      }
      // prefetch NEXT tile's A-fragment (hides eperm latency under consume)
      if (q < 2){
        int eidx = tb + 16 + m; eidx = eidx < NE ? eidx : NE-1;
        af = *(const bf16x8*)&eperm[(size_t)eidx*EDIM + q*8];
      }
      // same-wave LDS write->read: in-order DS pipe + compiler lgkmcnt, no barrier needed
      int tend = end < tb + 16 ? end : tb + 16;
      int e = tb;
      for (; e + 4 <= tend; e += 4){
        int sidx[4];
        #pragma unroll
        for (int i=0;i<4;i++) sidx[i] = srcs[e+i];
        u32 gx[4];
        #pragma unroll
        for (int i=0;i<4;i++) gx[i] = glv[(u32)sidx[i]<<6];
        float2 ev[4];
        #pragma unroll
        for (int i=0;i<4;i++) ev[i] = *(const float2*)&el[(e - tb + i)*ELP + 2*lane];
        #pragma unroll
        for (int i=0;i<4;i++){
          float xj0 = b2f_lo(gx[i]), xj1 = b2f_hi(gx[i]);
          float e0 = xj0 + gr0 + ev[i].x;
          float e1 = xj1 + gr1 + ev[i].y;
          e0 = fmaxf(e0, 0.2f*e0);
          e1 = fmaxf(e1, 0.2f*e1);
          float part = e0*att0 + e1*att1;          // log2-domain logit
          part = dpp_ror_add<1>(part);
          part = dpp_ror_add<2>(part);
          part = dpp_ror_add<4>(part);
          part = dpp_ror_add<8>(part);
          float nm = fmaxf(ms[i], part);
          float sc = fexp2(ms[i] - nm);            // -inf -> 0 on first edge
          float pp = fexp2(part - nm);
          ds[i] = ds[i]*sc + pp;
          o0[i] = o0[i]*sc + pp*xj0;
          o1[i] = o1[i]*sc + pp*xj1;
          ms[i] = nm;
        }
      }
      for (; e < tend; ++e){
        int s = srcs[e];
        u32 gx = glv[(u32)s<<6];
        float2 ev = *(const float2*)&el[(e - tb)*ELP + 2*lane];
        float xj0 = b2f_lo(gx), xj1 = b2f_hi(gx);
        float e0 = xj0 + gr0 + ev.x;
        float e1 = xj1 + gr1 + ev.y;
        e0 = fmaxf(e0, 0.2f*e0);
        e1 = fmaxf(e1, 0.2f*e1);
        float part = e0*att0 + e1*att1;
        part = dpp_ror_add<1>(part);
        part = dpp_ror_add<2>(part);
        part = dpp_ror_add<4>(part);
        part = dpp_ror_add<8>(part);
        float nm = fmaxf(ms[0], part);
        float sc = fexp2(ms[0] - nm);
        float pp = fexp2(part - nm);
        ds[0] = ds[0]*sc + pp;
        o0[0] = o0[0]*sc + pp*xj0;
        o1[0] = o1[0]*sc + pp*xj1;
        ms[0] = nm;
      }
    }
    // merge states (guard -inf: empty state contributes 0)
    float M = fmaxf(fmaxf(ms[0],ms[1]), fmaxf(ms[2],ms[3]));
    float D = 0.f, P0 = 0.f, P1 = 0.f;
    #pragma unroll
    for (int i=0;i<4;i++){
      if (ms[i] != -INFINITY){
        float sc = fexp2(ms[i] - M);
        D += sc*ds[i]; P0 += sc*o0[i]; P1 += sc*o1[i];
      }
    }
    float inv = 1.f/(D + 1e-16f);
    float v0 = P0*inv, v1 = P1*inv;
    s0 += v0; s1 += v1; sq0 += v0*v0; sq1 += v1*v1;
    ((float2*)agg)[(size_t)node*64 + lane] = make_float2(v0, v1);
  }
  // ---- block-reduce BN stats, then atomics into this block's replica ----
  {
    float* sp = &sEl[wv][0];
    sp[lane*4+0]=s0; sp[lane*4+1]=s1; sp[lane*4+2]=sq0; sp[lane*4+3]=sq1;
    __syncthreads();
    if (wv == 0){
      float a0=0,a1=0,b0=0,b1=0;
      #pragma unroll
      for (int w=0; w<4; ++w){
        a0 += sEl[w][lane*4+0]; a1 += sEl[w][lane*4+1];
        b0 += sEl[w][lane*4+2]; b1 += sEl[w][lane*4+3];
      }
      float* sr = stats + (blockIdx.x & (NREP-1))*256;
      int c0 = 2*lane;
      atomicAdd(&sr[c0],     a0); atomicAdd(&sr[c0+1],     a1);
      atomicAdd(&sr[DIM+c0], b0); atomicAdd(&sr[DIM+c0+1], b1);
    }
  }
}

// ---------------- launch ----------------
extern "C" void kernel_launch(void* const* d_in, const int* in_sizes, int n_in,
                              void* d_out, int out_size, void* d_ws, size_t ws_size,
                              hipStream_t stream){
  (void)in_sizes; (void)n_in; (void)out_size; (void)ws_size;
  const void* x    = d_in[0];
  const int* ei    = (const int*)d_in[1];
  const void* eattr= d_in[2];
  // d_in[9] = conv bias: cancels under BN mean-subtraction, skipped
  char* p = (char*)d_ws;
  auto alloc = [&](size_t b)->void*{ void* q = p; p += (b + 255) & ~(size_t)255; return q; };
  float* h      = (float*)alloc((size_t)NN*DIM*4);    // attn output (raw agg); BN fused downstream
  u16*   gl     = (u16*)  alloc((size_t)NN*DIM*2);
  u16*   gr     = (u16*)  alloc((size_t)NN*DIM*2);
  int*   offs   = (int*)  alloc((size_t)(NN+1)*4);
  int*   counts = (int*)  alloc((size_t)NN*4);
  int*   srcs   = (int*)  alloc((size_t)NE*4);
  u16*   eperm  = (u16*)  alloc((size_t)NE*EDIM*2);   // edge_attr in CSR order, bf16
  float* stats  = (float*)alloc((size_t)NL*NREP*256*4); // per-layer replicated BN stats
  int*   bsums  = (int*)  alloc(128*4);
  int*   flags  = (int*)  alloc(8);                   // [0]=fflag, [1]=iflag
  u16*   cpar   = (u16*)  alloc((size_t)SEG_TOTAL*2);

  int* fflag = flags;
  int* iflag = flags + 1;

  k_zero32<<<1,256,0,stream>>>(flags, 2);
  k_probe_f<<<1,256,0,stream>>>((const u16*)x, fflag);
  k_probe_i<<<4,256,0,stream>>>(ei, iflag);
  k_cvt_params<<<(SEG_TOTAL+255)/256,256,0,stream>>>(d_in[3], d_in[5], d_in[7], d_in[8],
      d_in[10], d_in[11], d_in[12], d_in[13], d_in[4], d_in[6], cpar, fflag);
  const u16* cWlT= cpar + SEG_WL;  const u16* cWrT= cpar + SEG_WR;
  const u16* cAtt= cpar + SEG_ATT;
  const u16* cGam= cpar + SEG_GAM; const u16* cBet= cpar + SEG_BET;
  const u16* cWfT= cpar + SEG_WF;  const u16* cBf = cpar + SEG_BF;
  const u16* cBl = cpar + SEG_BL;  const u16* cBr = cpar + SEG_BR;
  const u16* cWeT= cpar + SEG_WET;

  k_zero32<<<(NN+255)/256,256,0,stream>>>(counts, NN);
  k_zerof<<<(NL*NREP*256+255)/256,256,0,stream>>>(stats, NL*NREP*256);
  k_count<<<(NE+255)/256,256,0,stream>>>(ei, iflag, counts);
  const int nbA = (NN+1023)/1024;
  k_scanA<<<nbA,1024,0,stream>>>(counts, offs, bsums);
  k_scanB<<<1,1,0,stream>>>(bsums, offs, nbA);
  k_scanC<<<(NN+255)/256,256,0,stream>>>(offs, bsums);
  k_zero32<<<(NN+255)/256,256,0,stream>>>(counts, NN);
  k_fill<<<(NE+255)/256,256,0,stream>>>(ei, iflag, offs, counts, srcs, eperm, eattr, fflag);

  for (int L=0; L<NL; ++L){
    if (L == 0)
      k_gemm<<<dim3((NN+63)/64,2),256,0,stream>>>(x, 1, nullptr, nullptr, nullptr,
          cWlT + (size_t)L*DIM*DIM, cBl + L*DIM, gl,
          cWrT + (size_t)L*DIM*DIM, cBr + L*DIM, gr, 0, fflag);
    else
      k_gemm<<<dim3((NN+63)/64,2),256,0,stream>>>(h, 0, stats + (size_t)(L-1)*NREP*256,
          cGam + (L-1)*DIM, cBet + (L-1)*DIM,
          cWlT + (size_t)L*DIM*DIM, cBl + L*DIM, gl,
          cWrT + (size_t)L*DIM*DIM, cBr + L*DIM, gr, 0, fflag);
    // attn writes raw agg into h and accumulates BN stats for this layer
    k_attn<<<2048,256,0,stream>>>(offs, srcs, eperm,
        cWeT + (size_t)L*DIM*EDIM, cAtt + L*DIM, gl, gr, h, stats + (size_t)L*NREP*256);
  }
  // final projection with BN(layer2)+leaky fused on the input
  k_gemm<<<dim3((NN+63)/64,1),256,0,stream>>>(h, 0, stats + (size_t)2*NREP*256,
      cGam + 2*DIM, cBet + 2*DIM,
      cWfT, cBf, d_out, cWfT, cBf, d_out, 1, fflag);
}

// Round 8
// 1005.741 us; speedup vs baseline: 1.5615x; 1.0465x over previous
//
#include <hip/hip_runtime.h>

#define NN 100000
#define NE 1600000
#define DIM 128
#define EDIM 16
#define NL 3
#define NREP 8   // BN-stats atomic replicas (contention spreader)

typedef unsigned short u16;
typedef unsigned int u32;
typedef __attribute__((ext_vector_type(8))) short bf16x8;
typedef __attribute__((ext_vector_type(4))) float f32x4;

__device__ __forceinline__ float b2f(u16 u){ u32 x = ((u32)u)<<16; float f; __builtin_memcpy(&f,&x,4); return f; }
__device__ __forceinline__ float b2f_lo(u32 u){ u32 x = u<<16; float f; __builtin_memcpy(&f,&x,4); return f; }
__device__ __forceinline__ float b2f_hi(u32 u){ u32 x = u & 0xffff0000u; float f; __builtin_memcpy(&f,&x,4); return f; }
__device__ __forceinline__ u16 f2b(float f){ u32 x; __builtin_memcpy(&x,&f,4); u32 r = (x + 0x7fffu + ((x>>16)&1u))>>16; return (u16)r; }
__device__ __forceinline__ float fexp2(float x){ return __builtin_amdgcn_exp2f(x); }

// DPP rotation-add within 16-lane rows: part += ror<N>(part).
// NOTE: must stay a builtin (NOT inline asm) — the compiler inserts the required
// VALU-write -> DPP-read hazard s_nops; raw asm skips them (round-4 failure).
template<int N>
__device__ __forceinline__ float dpp_ror_add(float v){
  int x; __builtin_memcpy(&x, &v, 4);
  int y = __builtin_amdgcn_update_dpp(0, x, 0x120 | N, 0xF, 0xF, true);
  float r; __builtin_memcpy(&r, &y, 4);
  return v + r;
}

// ---------------- dtype probes ----------------
__global__ void k_probe_f(const u16* __restrict__ x, int* fflag){
  __shared__ int cnt;
  if (threadIdx.x==0) cnt = 0;
  __syncthreads();
  int sane = 0;
  for (int j=threadIdx.x; j<2048; j+=256){
    u16 w = x[j];
    int e = (w>>7)&0xFF;
    if (w==0 || (e>=100 && e<=140)) sane++;
  }
  atomicAdd(&cnt, sane);
  __syncthreads();
  if (threadIdx.x==0) *fflag = (cnt < 1900) ? 1 : 0;   // 1 => float32
}
__global__ void k_probe_i(const int* __restrict__ ei, int* iflag){
  int j = blockIdx.x*256 + threadIdx.x;
  if (j < 1024){ if (ei[2*j+1] != 0) atomicOr(iflag, 1); }  // !=0 => int32
}

// ---------------- utility ----------------
__global__ void k_zero32(int* p, int n){ int i = blockIdx.x*256 + threadIdx.x; if (i<n) p[i]=0; }
__global__ void k_zerof(float* p, int n){ int i = blockIdx.x*256 + threadIdx.x; if (i<n) p[i]=0.f; }

// canonical bf16 params; Wl/Wr/Wf stored TRANSPOSED (dst[c][k] = src[k][c])
// WET = We transposed per layer: WeT[l][c][k] = We[l][k][c]
#define SEG_WL    0
#define SEG_WR    49152
#define SEG_WE    98304
#define SEG_ATT   104448
#define SEG_GAM   104832
#define SEG_BET   105216
#define SEG_WF    105600
#define SEG_BF    121984
#define SEG_BL    122112
#define SEG_BR    122496
#define SEG_WET   122880
#define SEG_TOTAL 129024

__global__ void k_cvt_params(const void* Wl, const void* Wr, const void* We, const void* att,
                             const void* gam, const void* bet, const void* Wf, const void* bf,
                             const void* bl, const void* br,
                             u16* __restrict__ dst, const int* __restrict__ fflag){
  int i = blockIdx.x*256 + threadIdx.x;
  if (i >= SEG_TOTAL) return;
  const void* src; int off;
  if (i < SEG_WR){                       // Wl^T
    int o = i - SEG_WL; int l = o>>14, r = o&16383, c = r>>7, k = r&127;
    src = Wl; off = (l<<14)|(k<<7)|c;
  } else if (i < SEG_WE){                // Wr^T
    int o = i - SEG_WR; int l = o>>14, r = o&16383, c = r>>7, k = r&127;
    src = Wr; off = (l<<14)|(k<<7)|c;
  } else if (i < SEG_ATT){ src = We;  off = i - SEG_WE; }
  else if (i < SEG_GAM)  { src = att; off = i - SEG_ATT; }
  else if (i < SEG_BET)  { src = gam; off = i - SEG_GAM; }
  else if (i < SEG_WF)   { src = bet; off = i - SEG_BET; }
  else if (i < SEG_BF){                  // Wf^T
    int o = i - SEG_WF; int c = o>>7, k = o&127;
    src = Wf; off = (k<<7)|c;
  }
  else if (i < SEG_BL)   { src = bf;  off = i - SEG_BF; }
  else if (i < SEG_BR)   { src = bl;  off = i - SEG_BL; }
  else if (i < SEG_WET)  { src = br;  off = i - SEG_BR; }
  else {                                 // We^T: [l][c][k] <- We[l][k][c]
    int o = i - SEG_WET; int l = o>>11, r = o&2047, c = r>>4, k = r&15;
    src = We; off = (l<<11)|(k<<7)|c;
  }
  dst[i] = (*fflag) ? f2b(((const float*)src)[off]) : ((const u16*)src)[off];
}

// ---------------- CSR build ----------------
__global__ void k_count(const int* __restrict__ ei, const int* __restrict__ iflag, int* __restrict__ counts){
  int e = blockIdx.x*256 + threadIdx.x; if (e >= NE) return;
  int d;
  if (*iflag) d = ei[NE + e];
  else        d = (int)((const long long*)ei)[NE + e];
  atomicAdd(&counts[d], 1);
}
__global__ void k_scanA(const int* __restrict__ counts, int* __restrict__ offs, int* __restrict__ bsums){
  __shared__ int s[1024];
  int t = threadIdx.x; int i = blockIdx.x*1024 + t;
  int v = (i < NN) ? counts[i] : 0;
  s[t] = v; __syncthreads();
  for (int off=1; off<1024; off<<=1){
    int x = (t>=off) ? s[t-off] : 0;
    __syncthreads();
    s[t] += x;
    __syncthreads();
  }
  if (i < NN) offs[i] = s[t] - v;
  if (t == 1023) bsums[blockIdx.x] = s[1023];
}
__global__ void k_scanB(int* bsums, int* offs, int nb){
  if (threadIdx.x==0 && blockIdx.x==0){
    int run = 0;
    for (int j=0;j<nb;j++){ int tmp=bsums[j]; bsums[j]=run; run+=tmp; }
    offs[NN] = run;
  }
}
__global__ void k_scanC(int* __restrict__ offs, const int* __restrict__ bsums){
  int i = blockIdx.x*256 + threadIdx.x;
  if (i < NN) offs[i] += bsums[i>>10];
}

// fill CSR: srcs + edge_attr permuted into CSR order as bf16 (eperm).
// Slot index comes from atomicSub on the leftover degree counts (k_count's output),
// eliminating the second counts-zeroing dispatch. Order within a node is arbitrary
// (was already atomic-nondeterministic).
__global__ void k_fill(const int* __restrict__ ei, const int* __restrict__ iflag,
                       const int* __restrict__ offs, int* __restrict__ counts,
                       int* __restrict__ srcs, u16* __restrict__ eperm,
                       const void* __restrict__ eattr, const int* __restrict__ fflag){
  int e = blockIdx.x*256 + threadIdx.x; if (e >= NE) return;
  int s, d;
  if (*iflag){ s = ei[e]; d = ei[NE + e]; }
  else { const long long* e64 = (const long long*)ei; s = (int)e64[e]; d = (int)e64[NE + e]; }
  int pos = offs[d] + atomicSub(&counts[d], 1) - 1;
  srcs[pos] = s;
  uint4 lo, hi;
  if (*fflag){
    const float4* s4 = (const float4*)((const float*)eattr + (size_t)e*EDIM);
    float4 a = s4[0], b = s4[1], c = s4[2], dd = s4[3];
    lo.x = (u32)f2b(a.x) | ((u32)f2b(a.y)<<16); lo.y = (u32)f2b(a.z) | ((u32)f2b(a.w)<<16);
    lo.z = (u32)f2b(b.x) | ((u32)f2b(b.y)<<16); lo.w = (u32)f2b(b.z) | ((u32)f2b(b.w)<<16);
    hi.x = (u32)f2b(c.x) | ((u32)f2b(c.y)<<16); hi.y = (u32)f2b(c.z) | ((u32)f2b(c.w)<<16);
    hi.z = (u32)f2b(dd.x)| ((u32)f2b(dd.y)<<16);hi.w = (u32)f2b(dd.z)| ((u32)f2b(dd.w)<<16);
  } else {
    const uint4* s4 = (const uint4*)((const u16*)eattr + (size_t)e*EDIM);
    lo = s4[0]; hi = s4[1];
  }
  uint4* dst = (uint4*)(eperm + (size_t)pos*EDIM);
  dst[0] = lo; dst[1] = hi;
}

// ---------------- MFMA node GEMM with optional fused BN+leaky on the input ----------------
// out[n][c] = sum_k f(in[n][k])*W[k][c] + b[c], f = BN-affine + leaky(0.02) when st!=null.
// st points at NREP stats replicas of [256] (sums in [0,128), sq-sums in [128,256)).
#define LSTR 136   // padded LDS row stride (bf16 elems): +16B breaks bank conflicts
__global__ __launch_bounds__(256) void k_gemm(const void* __restrict__ in, int in_raw,
    const float* __restrict__ st, const u16* __restrict__ gm, const u16* __restrict__ bt,
    const u16* __restrict__ WT0, const u16* __restrict__ b0, void* __restrict__ out0,
    const u16* __restrict__ WT1, const u16* __restrict__ b1, void* __restrict__ out1,
    int store_f32, const int* __restrict__ fflag)
{
  __shared__ __align__(16) u16 Xs[64*LSTR];
  __shared__ __align__(16) u16 Ws[128*LSTR];
  __shared__ __align__(16) float sA[DIM], sB[DIM];
  const u16* WT = blockIdx.y ? WT1 : WT0;
  const u16* bi = blockIdx.y ? b1 : b0;
  void* out     = blockIdx.y ? out1 : out0;
  int t = threadIdx.x;
  int n0 = blockIdx.x*64;
  // stage W^T (128x128 bf16 = 2048 uint4), coalesced
  const uint4* w4 = (const uint4*)WT;
  for (int p = t; p < 2048; p += 256){
    int c = p >> 4, k16 = p & 15;
    *(uint4*)&Ws[c*LSTR + k16*8] = w4[p];
  }
  // BN affine coefficients: y = v*A[c] + B[c] (sum the NREP replicas first)
  if (st && t < DIM){
    float sum = 0.f, sqs = 0.f;
    #pragma unroll
    for (int r = 0; r < NREP; ++r){
      sum += st[r*256 + t];
      sqs += st[r*256 + DIM + t];
    }
    const float invN = 1.f/(float)NN;
    float mu = sum*invN;
    float va = sqs*invN - mu*mu;
    float rs = rsqrtf(fmaxf(va, 0.f) + 1e-5f);
    float A = rs*b2f(gm[t]);
    sA[t] = A;
    sB[t] = b2f(bt[t]) - mu*A;
  }
  __syncthreads();
  // stage X (64x128 -> bf16), optional BN+leaky
  for (int p = t; p < 2048; p += 256){
    int r = p >> 5, c4 = p & 31;
    int n = n0 + r;
    uint2 pk = make_uint2(0,0);
    if (n < NN){
      if (in_raw && !(*fflag)){
        pk = *(const uint2*)((const u16*)in + (size_t)n*DIM + c4*4);
      } else {
        float4 v = *(const float4*)((const float*)in + (size_t)n*DIM + c4*4);
        if (st){
          int c = c4*4;
          float4 Af = *(const float4*)&sA[c];
          float4 Bf = *(const float4*)&sB[c];
          v.x = v.x*Af.x + Bf.x; v.x = fmaxf(v.x, 0.02f*v.x);
          v.y = v.y*Af.y + Bf.y; v.y = fmaxf(v.y, 0.02f*v.y);
          v.z = v.z*Af.z + Bf.z; v.z = fmaxf(v.z, 0.02f*v.z);
          v.w = v.w*Af.w + Bf.w; v.w = fmaxf(v.w, 0.02f*v.w);
        }
        pk.x = (u32)f2b(v.x) | ((u32)f2b(v.y)<<16);
        pk.y = (u32)f2b(v.z) | ((u32)f2b(v.w)<<16);
      }
    }
    *(uint2*)&Xs[r*LSTR + c4*4] = pk;
  }
  __syncthreads();
  int lane = t & 63, wv = t >> 6;
  int m = lane & 15, q = lane >> 4;
  f32x4 acc[8];
  #pragma unroll
  for (int i=0;i<8;i++) acc[i] = (f32x4){0.f,0.f,0.f,0.f};
  #pragma unroll
  for (int ks=0; ks<4; ks++){
    bf16x8 af = *(const bf16x8*)&Xs[(wv*16 + m)*LSTR + ks*32 + q*8];
    #pragma unroll
    for (int nt=0; nt<8; nt++){
      bf16x8 bfr = *(const bf16x8*)&Ws[(nt*16 + m)*LSTR + ks*32 + q*8];
      acc[nt] = __builtin_amdgcn_mfma_f32_16x16x32_bf16(af, bfr, acc[nt], 0, 0, 0);
    }
  }
  bool f32out = store_f32 && (*fflag);
  #pragma unroll
  for (int nt=0; nt<8; nt++){
    int col = nt*16 + m;
    float bvv = b2f(bi[col]);
    #pragma unroll
    for (int r=0;r<4;r++){
      int row = n0 + wv*16 + q*4 + r;
      if (row < NN){
        float val = acc[nt][r] + bvv;
        if (f32out) ((float*)out)[(size_t)row*DIM + col] = val;
        else        ((u16*)out)[(size_t)row*DIM + col] = f2b(val);
      }
    }
  }
}

// ---------------- attention (+ fused BN-stats, replica-scattered atomics) ----------------
// One wave per node (grid-stride). Per 16-edge CSR tile, el = eperm_tile @ We on the
// matrix pipe: mfma(af, bwe[tc]) -> D[edge][ch], scattered per-reg into el[edge][ELP]
// (2-way banks = free). Consume loop is 8-wide batched (8 gathers in flight) to cover
// the ~400cy L2/L3 gather latency at ~3.2 waves/SIMD occupancy; then 4-wide + scalar
// remainder. Online softmax with builtin-DPP rotation reduce; BN stats accumulated in
// registers, block-merged, atomics into per-block replica (8x contention spread).
#define ELP 132  // el row stride (f32): 528B/row -> 2-way bank aliasing on write+read (free)
__global__ __launch_bounds__(256,4) void k_attn(const int* __restrict__ offs, const int* __restrict__ srcs,
    const u16* __restrict__ eperm, const u16* __restrict__ WeT, const u16* __restrict__ att,
    const u16* __restrict__ gl, const u16* __restrict__ gr, float* __restrict__ agg,
    float* __restrict__ stats)
{
  __shared__ __align__(16) float sEl[4][16*ELP];   // per-wave el tiles, 33.8 KB
  int t = threadIdx.x;
  int lane = t & 63, wv = t >> 6;
  int m = lane & 15, q = lane >> 4;
  // loop-invariant fragments of We^T: bwe[tc] holds WeT[tc*16+m][q*8..q*8+7] (zero for k>=16)
  bf16x8 bwe[8];
  #pragma unroll
  for (int tc = 0; tc < 8; ++tc){
    if (q < 2) bwe[tc] = *(const bf16x8*)&WeT[(tc*16 + m)*16 + q*8];
    else       bwe[tc] = (bf16x8){0,0,0,0,0,0,0,0};
  }
  // fold log2(e) into att so exponentials are native exp2 (alpha mathematically identical)
  const float LOG2E = 1.442695041f;
  float att0 = b2f(att[2*lane])*LOG2E, att1 = b2f(att[2*lane+1])*LOG2E;
  float* el = &sEl[wv][0];
  const u32* glv = (const u32*)gl + lane;   // lane folded into base
  float s0=0.f, s1=0.f, sq0=0.f, sq1=0.f;   // BN-stats accumulators (lane owns chs 2l,2l+1)

  for (int node = blockIdx.x*4 + wv; node < NN; node += gridDim.x*4){
    u32 g = ((const u32*)gr)[(size_t)node*64 + lane];
    float gr0 = b2f_lo(g), gr1 = b2f_hi(g);
    float ms[4], ds[4], o0[4], o1[4];
    #pragma unroll
    for (int i=0;i<4;i++){ ms[i] = -INFINITY; ds[i]=0.f; o0[i]=0.f; o1[i]=0.f; }
    int beg = offs[node], end = offs[node+1];
    // per-edge softmax core; state index i in [0,4)
    auto edge_core = [&](int i, u32 gxv, float2 evv){
      float xj0 = b2f_lo(gxv), xj1 = b2f_hi(gxv);
      float e0 = xj0 + gr0 + evv.x;
      float e1 = xj1 + gr1 + evv.y;
      e0 = fmaxf(e0, 0.2f*e0);
      e1 = fmaxf(e1, 0.2f*e1);
      float part = e0*att0 + e1*att1;          // log2-domain logit
      part = dpp_ror_add<1>(part);
      part = dpp_ror_add<2>(part);
      part = dpp_ror_add<4>(part);
      part = dpp_ror_add<8>(part);
      float nm = fmaxf(ms[i], part);
      float sc = fexp2(ms[i] - nm);            // -inf -> 0 on first edge
      float pp = fexp2(part - nm);
      ds[i] = ds[i]*sc + pp;
      o0[i] = o0[i]*sc + pp*xj0;
      o1[i] = o1[i]*sc + pp*xj1;
      ms[i] = nm;
    };
    // prefetch first tile's A-fragment
    bf16x8 af = (bf16x8){0,0,0,0,0,0,0,0};
    if (q < 2 && beg < end){
      int eidx = beg + m; eidx = eidx < NE ? eidx : NE-1;
      af = *(const bf16x8*)&eperm[(size_t)eidx*EDIM + q*8];
    }
    for (int tb = beg; tb < end; tb += 16){
      // ---- el tile on matrix pipe; per-reg scatter (2-way banks = free) ----
      #pragma unroll
      for (int tc = 0; tc < 8; ++tc){
        f32x4 d = __builtin_amdgcn_mfma_f32_16x16x32_bf16(af, bwe[tc], (f32x4){0.f,0.f,0.f,0.f}, 0, 0, 0);
        #pragma unroll
        for (int r = 0; r < 4; ++r)
          el[(q*4 + r)*ELP + tc*16 + m] = d[r];     // edge=q*4+r, ch=tc*16+m
      }
      // prefetch NEXT tile's A-fragment (hides eperm latency under consume)
      if (q < 2){
        int eidx = tb + 16 + m; eidx = eidx < NE ? eidx : NE-1;
        af = *(const bf16x8*)&eperm[(size_t)eidx*EDIM + q*8];
      }
      // same-wave LDS write->read: in-order DS pipe + compiler lgkmcnt, no barrier needed
      int tend = end < tb + 16 ? end : tb + 16;
      int e = tb;
      for (; e + 8 <= tend; e += 8){
        int sidx[8];
        #pragma unroll
        for (int i=0;i<8;i++) sidx[i] = srcs[e+i];
        u32 gx[8];
        #pragma unroll
        for (int i=0;i<8;i++) gx[i] = glv[(u32)sidx[i]<<6];
        float2 ev[8];
        #pragma unroll
        for (int i=0;i<8;i++) ev[i] = *(const float2*)&el[(e - tb + i)*ELP + 2*lane];
        #pragma unroll
        for (int i=0;i<8;i++) edge_core(i & 3, gx[i], ev[i]);
      }
      for (; e + 4 <= tend; e += 4){
        int sidx[4];
        #pragma unroll
        for (int i=0;i<4;i++) sidx[i] = srcs[e+i];
        u32 gx[4];
        #pragma unroll
        for (int i=0;i<4;i++) gx[i] = glv[(u32)sidx[i]<<6];
        float2 ev[4];
        #pragma unroll
        for (int i=0;i<4;i++) ev[i] = *(const float2*)&el[(e - tb + i)*ELP + 2*lane];
        #pragma unroll
        for (int i=0;i<4;i++) edge_core(i, gx[i], ev[i]);
      }
      for (; e < tend; ++e){
        u32 gx = glv[(u32)srcs[e]<<6];
        float2 ev = *(const float2*)&el[(e - tb)*ELP + 2*lane];
        edge_core(0, gx, ev);
      }
    }
    // merge states (guard -inf: empty state contributes 0)
    float M = fmaxf(fmaxf(ms[0],ms[1]), fmaxf(ms[2],ms[3]));
    float D = 0.f, P0 = 0.f, P1 = 0.f;
    #pragma unroll
    for (int i=0;i<4;i++){
      if (ms[i] != -INFINITY){
        float sc = fexp2(ms[i] - M);
        D += sc*ds[i]; P0 += sc*o0[i]; P1 += sc*o1[i];
      }
    }
    float inv = 1.f/(D + 1e-16f);
    float v0 = P0*inv, v1 = P1*inv;
    s0 += v0; s1 += v1; sq0 += v0*v0; sq1 += v1*v1;
    ((float2*)agg)[(size_t)node*64 + lane] = make_float2(v0, v1);
  }
  // ---- block-reduce BN stats, then atomics into this block's replica ----
  {
    float* sp = &sEl[wv][0];
    sp[lane*4+0]=s0; sp[lane*4+1]=s1; sp[lane*4+2]=sq0; sp[lane*4+3]=sq1;
    __syncthreads();
    if (wv == 0){
      float a0=0,a1=0,b0=0,b1=0;
      #pragma unroll
      for (int w=0; w<4; ++w){
        a0 += sEl[w][lane*4+0]; a1 += sEl[w][lane*4+1];
        b0 += sEl[w][lane*4+2]; b1 += sEl[w][lane*4+3];
      }
      float* sr = stats + (blockIdx.x & (NREP-1))*256;
      int c0 = 2*lane;
      atomicAdd(&sr[c0],     a0); atomicAdd(&sr[c0+1],     a1);
      atomicAdd(&sr[DIM+c0], b0); atomicAdd(&sr[DIM+c0+1], b1);
    }
  }
}

// ---------------- launch ----------------
extern "C" void kernel_launch(void* const* d_in, const int* in_sizes, int n_in,
                              void* d_out, int out_size, void* d_ws, size_t ws_size,
                              hipStream_t stream){
  (void)in_sizes; (void)n_in; (void)out_size; (void)ws_size;
  const void* x    = d_in[0];
  const int* ei    = (const int*)d_in[1];
  const void* eattr= d_in[2];
  // d_in[9] = conv bias: cancels under BN mean-subtraction, skipped
  char* p = (char*)d_ws;
  auto alloc = [&](size_t b)->void*{ void* q = p; p += (b + 255) & ~(size_t)255; return q; };
  float* h      = (float*)alloc((size_t)NN*DIM*4);    // attn output (raw agg); BN fused downstream
  u16*   gl     = (u16*)  alloc((size_t)NN*DIM*2);
  u16*   gr     = (u16*)  alloc((size_t)NN*DIM*2);
  int*   offs   = (int*)  alloc((size_t)(NN+1)*4);
  int*   counts = (int*)  alloc((size_t)NN*4);
  int*   srcs   = (int*)  alloc((size_t)NE*4);
  u16*   eperm  = (u16*)  alloc((size_t)NE*EDIM*2);   // edge_attr in CSR order, bf16
  float* stats  = (float*)alloc((size_t)NL*NREP*256*4); // per-layer replicated BN stats
  int*   bsums  = (int*)  alloc(128*4);
  int*   flags  = (int*)  alloc(8);                   // [0]=fflag, [1]=iflag
  u16*   cpar   = (u16*)  alloc((size_t)SEG_TOTAL*2);

  int* fflag = flags;
  int* iflag = flags + 1;

  k_zero32<<<1,256,0,stream>>>(flags, 2);
  k_probe_f<<<1,256,0,stream>>>((const u16*)x, fflag);
  k_probe_i<<<4,256,0,stream>>>(ei, iflag);
  k_cvt_params<<<(SEG_TOTAL+255)/256,256,0,stream>>>(d_in[3], d_in[5], d_in[7], d_in[8],
      d_in[10], d_in[11], d_in[12], d_in[13], d_in[4], d_in[6], cpar, fflag);
  const u16* cWlT= cpar + SEG_WL;  const u16* cWrT= cpar + SEG_WR;
  const u16* cAtt= cpar + SEG_ATT;
  const u16* cGam= cpar + SEG_GAM; const u16* cBet= cpar + SEG_BET;
  const u16* cWfT= cpar + SEG_WF;  const u16* cBf = cpar + SEG_BF;
  const u16* cBl = cpar + SEG_BL;  const u16* cBr = cpar + SEG_BR;
  const u16* cWeT= cpar + SEG_WET;

  k_zero32<<<(NN+255)/256,256,0,stream>>>(counts, NN);
  k_zerof<<<(NL*NREP*256+255)/256,256,0,stream>>>(stats, NL*NREP*256);
  k_count<<<(NE+255)/256,256,0,stream>>>(ei, iflag, counts);
  const int nbA = (NN+1023)/1024;
  k_scanA<<<nbA,1024,0,stream>>>(counts, offs, bsums);
  k_scanB<<<1,1,0,stream>>>(bsums, offs, nbA);
  k_scanC<<<(NN+255)/256,256,0,stream>>>(offs, bsums);
  k_fill<<<(NE+255)/256,256,0,stream>>>(ei, iflag, offs, counts, srcs, eperm, eattr, fflag);

  for (int L=0; L<NL; ++L){
    if (L == 0)
      k_gemm<<<dim3((NN+63)/64,2),256,0,stream>>>(x, 1, nullptr, nullptr, nullptr,
          cWlT + (size_t)L*DIM*DIM, cBl + L*DIM, gl,
          cWrT + (size_t)L*DIM*DIM, cBr + L*DIM, gr, 0, fflag);
    else
      k_gemm<<<dim3((NN+63)/64,2),256,0,stream>>>(h, 0, stats + (size_t)(L-1)*NREP*256,
          cGam + (L-1)*DIM, cBet + (L-1)*DIM,
          cWlT + (size_t)L*DIM*DIM, cBl + L*DIM, gl,
          cWrT + (size_t)L*DIM*DIM, cBr + L*DIM, gr, 0, fflag);
    // attn writes raw agg into h and accumulates BN stats for this layer
    k_attn<<<2048,256,0,stream>>>(offs, srcs, eperm,
        cWeT + (size_t)L*DIM*EDIM, cAtt + L*DIM, gl, gr, h, stats + (size_t)L*NREP*256);
  }
  // final projection with BN(layer2)+leaky fused on the input
  k_gemm<<<dim3((NN+63)/64,1),256,0,stream>>>(h, 0, stats + (size_t)2*NREP*256,
      cGam + 2*DIM, cBet + 2*DIM,
      cWfT, cBf, d_out, cWfT, cBf, d_out, 1, fflag);
}